// Round 7
// baseline (1353.910 us; speedup 1.0000x reference)
//
#include <hip/hip_runtime.h>
#include <hip/hip_bf16.h>

#define NEGS 0.2f

// ---------------- CSR build ----------------
__global__ void k_degi(const int* __restrict__ dst, int* __restrict__ deg, int E) {
    int e = blockIdx.x * blockDim.x + threadIdx.x;
    if (e < E) atomicAdd(&deg[dst[e]], 1);
}

__global__ __launch_bounds__(1024)
void k_scan(const int* __restrict__ deg, int* __restrict__ rowptr,
            float* __restrict__ norm, int N) {
    __shared__ int ssum[1024];
    int t = threadIdx.x;
    int chunk = (N + 1023) >> 10;
    int b = min(t * chunk, N), e = min(b + chunk, N);
    int s = 0;
    for (int i = b; i < e; ++i) s += deg[i];
    ssum[t] = s;
    __syncthreads();
    for (int off = 1; off < 1024; off <<= 1) {
        int v = (t >= off) ? ssum[t - off] : 0;
        __syncthreads();
        ssum[t] += v;
        __syncthreads();
    }
    int run = (t == 0) ? 0 : ssum[t - 1];
    for (int i = b; i < e; ++i) { rowptr[i] = run; run += deg[i]; }
    if (t == 0) rowptr[N] = ssum[1023];
    for (int i = b; i < e; ++i) norm[i] = rsqrtf(fmaxf((float)deg[i], 1.0f));
}

__global__ void k_fill(const int* __restrict__ src, const int* __restrict__ dst,
                       const int* __restrict__ rowptr, int* __restrict__ cnt,
                       int* __restrict__ csr_src, int E) {
    int e = blockIdx.x * blockDim.x + threadIdx.x;
    if (e >= E) return;
    int d = dst[e];
    int pos = rowptr[d] + atomicAdd(&cnt[d], 1);
    csr_src[pos] = src[e];
}

// ---------------- GEMM v3: C[N,160] = A[N,K] @ B[K,160] -----------------
// 32 rows x 160 cols per block, 320 threads (4 rows x 4 cols each).
// Per k-step: 2x ds_read_b128 feeding 16 FMAs (FMA-dominant issue).
// Double-buffered LDS, one barrier per 16-k chunk.
__global__ __launch_bounds__(320)
void k_gemm160(const float* __restrict__ A, const float* __restrict__ B,
               const float* __restrict__ bias, const float* __restrict__ rowscale,
               float* __restrict__ C, int Nrows, int K) {
    constexpr int M = 160;
    __shared__ __align__(16) float As[2][16][36];    // [k][row], padded
    __shared__ __align__(16) float Bs[2][16][160];   // [k][col]
    const int tid = threadIdx.x;
    const int tx = tid % 40;          // col group: cols tx*4 .. tx*4+3
    const int ty = tid / 40;          // row group 0..7: rows ty*4 .. ty*4+3
    const int r0 = blockIdx.x * 32;
    const int nT = (K + 15) / 16;

    float4 st[3];                      // staged global values (A: 128 slots, B: 640 slots)

    auto loadStage = [&](int t) {
        #pragma unroll
        for (int j = 0; j < 3; ++j) {
            int idx = tid + j * 320;
            st[j] = make_float4(0.f, 0.f, 0.f, 0.f);
            if (idx < 128) {                       // A: 32 rows x 4 k-quads
                int r = idx >> 2, kq = (idx & 3) * 4;
                int row = r0 + r, kb = t * 16 + kq;
                if (row < Nrows) {
                    if (kb + 3 < K) {
                        st[j] = *reinterpret_cast<const float4*>(&A[(size_t)row * K + kb]);
                    } else {
                        float tmp[4] = {0.f, 0.f, 0.f, 0.f};
                        #pragma unroll
                        for (int q = 0; q < 4; ++q)
                            if (kb + q < K) tmp[q] = A[(size_t)row * K + kb + q];
                        st[j] = make_float4(tmp[0], tmp[1], tmp[2], tmp[3]);
                    }
                }
            } else if (idx < 768) {                // B: 16 k x 40 col-quads
                int bidx = idx - 128;
                int kk = bidx / 40, c4 = (bidx % 40) * 4;
                int kb = t * 16 + kk;
                if (kb < K)
                    st[j] = *reinterpret_cast<const float4*>(&B[(size_t)kb * M + c4]);
            }
        }
    };
    auto storeStage = [&](int buf) {
        #pragma unroll
        for (int j = 0; j < 3; ++j) {
            int idx = tid + j * 320;
            if (idx < 128) {
                int r = idx >> 2, kq = (idx & 3) * 4;
                As[buf][kq + 0][r] = st[j].x; As[buf][kq + 1][r] = st[j].y;
                As[buf][kq + 2][r] = st[j].z; As[buf][kq + 3][r] = st[j].w;
            } else if (idx < 768) {
                int bidx = idx - 128;
                int kk = bidx / 40, c4 = (bidx % 40) * 4;
                *reinterpret_cast<float4*>(&Bs[buf][kk][c4]) = st[j];
            }
        }
    };

    float4 acc[4] = {};                 // acc[r] = 4 cols for row r
    loadStage(0);
    storeStage(0);
    __syncthreads();
    for (int t = 0; t < nT; ++t) {
        int cur = t & 1;
        if (t + 1 < nT) loadStage(t + 1);       // global->reg, overlaps FMAs
        #pragma unroll
        for (int kk = 0; kk < 16; ++kk) {
            float4 av = *reinterpret_cast<const float4*>(&As[cur][kk][ty * 4]);
            float4 bv = *reinterpret_cast<const float4*>(&Bs[cur][kk][tx * 4]);
            acc[0].x += av.x * bv.x; acc[0].y += av.x * bv.y; acc[0].z += av.x * bv.z; acc[0].w += av.x * bv.w;
            acc[1].x += av.y * bv.x; acc[1].y += av.y * bv.y; acc[1].z += av.y * bv.z; acc[1].w += av.y * bv.w;
            acc[2].x += av.z * bv.x; acc[2].y += av.z * bv.y; acc[2].z += av.z * bv.z; acc[2].w += av.z * bv.w;
            acc[3].x += av.w * bv.x; acc[3].y += av.w * bv.y; acc[3].z += av.w * bv.z; acc[3].w += av.w * bv.w;
        }
        if (t + 1 < nT) storeStage(cur ^ 1);
        __syncthreads();
    }

    float4 bv = make_float4(0.f, 0.f, 0.f, 0.f);
    if (bias) bv = *reinterpret_cast<const float4*>(&bias[tx * 4]);
    #pragma unroll
    for (int r = 0; r < 4; ++r) {
        int row = r0 + ty * 4 + r;
        if (row >= Nrows) continue;
        float sc = rowscale ? rowscale[row] : 1.0f;
        float4 v = acc[r];
        v.x = (v.x + bv.x) * sc; v.y = (v.y + bv.y) * sc;
        v.z = (v.z + bv.z) * sc; v.w = (v.w + bv.w) * sc;
        *reinterpret_cast<float4*>(&C[(size_t)row * M + tx * 4]) = v;
    }
}

// ---------------- small GEMM for Wout ----------------
__global__ __launch_bounds__(256)
void k_gemv10(const float* __restrict__ A, const float* __restrict__ B,
              float* __restrict__ C, int Nrows, int K) {
    __shared__ float Bs[160 * 10];
    for (int i = threadIdx.x; i < K * 10; i += 256) Bs[i] = B[i];
    __syncthreads();
    int row = blockIdx.x * 256 + threadIdx.x;
    if (row >= Nrows) return;
    float acc[10] = {};
    const float4* a = reinterpret_cast<const float4*>(A + (size_t)row * K);
    for (int kq = 0; kq < K / 4; ++kq) {
        float4 v = a[kq];
        int k = kq * 4;
        #pragma unroll
        for (int j = 0; j < 10; ++j)
            acc[j] += v.x * Bs[(k + 0) * 10 + j] + v.y * Bs[(k + 1) * 10 + j]
                    + v.z * Bs[(k + 2) * 10 + j] + v.w * Bs[(k + 3) * 10 + j];
    }
    #pragma unroll
    for (int j = 0; j < 10; ++j) C[(size_t)row * 10 + j] = acc[j];
}

// ---------------- attention logits el/er ----------------
__global__ void k_elr32(const float* __restrict__ feat, const float* __restrict__ al,
                        const float* __restrict__ ar, float* __restrict__ el,
                        float* __restrict__ er, int N, int H) {
    int i = blockIdx.x * blockDim.x + threadIdx.x;
    if (i >= N * H) return;
    int h = i % H;
    const float4* f = (const float4*)(feat + (size_t)i * 32);
    const float4* a = (const float4*)(al + h * 32);
    const float4* b = (const float4*)(ar + h * 32);
    float sl = 0.0f, sr = 0.0f;
    #pragma unroll
    for (int d = 0; d < 8; d++) {
        float4 v = f[d], x = a[d], y = b[d];
        sl += v.x * x.x + v.y * x.y + v.z * x.z + v.w * x.w;
        sr += v.x * y.x + v.y * y.y + v.z * y.z + v.w * y.w;
    }
    el[i] = sl; er[i] = sr;
}

__global__ void k_elr_gen(const float* __restrict__ feat, const float* __restrict__ al,
                          const float* __restrict__ ar, float* __restrict__ el,
                          float* __restrict__ er, int N, int H, int D) {
    int i = blockIdx.x * blockDim.x + threadIdx.x;
    if (i >= N * H) return;
    int h = i % H;
    const float* f = feat + (size_t)i * D;
    const float* a = al + h * D;
    const float* b = ar + h * D;
    float sl = 0.0f, sr = 0.0f;
    for (int d = 0; d < D; d++) { float v = f[d]; sl += v * a[d]; sr += v * b[d]; }
    el[i] = sl; er[i] = sr;
}

// ---------------- fused GAT: online softmax + float4 weighted gather ----
template<int H, int D>
__global__ __launch_bounds__(64)
void k_gat_fused(const int* __restrict__ rowptr, const int* __restrict__ csr_src,
                 const float* __restrict__ el, const float* __restrict__ er,
                 const float* __restrict__ feat, const float* __restrict__ res,
                 float* __restrict__ out, int relu_mode) {
    constexpr int HD = H * D;
    const int n = blockIdx.x;
    const int lane = threadIdx.x;
    const int beg = rowptr[n], end = rowptr[n + 1];

    float erh[H];
    #pragma unroll
    for (int h = 0; h < H; ++h) erh[h] = er[n * H + h];

    float m[H], ssum[H];
    #pragma unroll
    for (int h = 0; h < H; ++h) { m[h] = -1e30f; ssum[h] = 0.0f; }
    for (int j = beg + lane; j < end; j += 64) {
        int s = csr_src[j];
        #pragma unroll
        for (int h = 0; h < H; ++h) {
            float x = el[s * H + h] + erh[h];
            x = (x > 0.0f) ? x : (NEGS * x);
            float mn = fmaxf(m[h], x);
            ssum[h] = ssum[h] * __expf(m[h] - mn) + __expf(x - mn);
            m[h] = mn;
        }
    }
    float inv[H];
    #pragma unroll
    for (int h = 0; h < H; ++h) {
        #pragma unroll
        for (int off = 32; off; off >>= 1) {
            float mo = __shfl_xor(m[h], off, 64);
            float so = __shfl_xor(ssum[h], off, 64);
            float mn = fmaxf(m[h], mo);
            ssum[h] = ssum[h] * __expf(m[h] - mn) + so * __expf(mo - mn);
            m[h] = mn;
        }
        inv[h] = (ssum[h] > 0.0f) ? 1.0f / ssum[h] : 0.0f;
    }

    __shared__ float s_alpha[64 * H];
    __shared__ int   s_src[64];

    if constexpr ((D & 3) == 0) {
        constexpr int NV = HD / 4;
        const int hc = (lane * 4) / D;
        float4 acc = make_float4(0.f, 0.f, 0.f, 0.f);
        for (int chunk = beg; chunk < end; chunk += 64) {
            int j = chunk + lane;
            if (j < end) {
                int s = csr_src[j];
                s_src[lane] = s;
                #pragma unroll
                for (int h = 0; h < H; ++h) {
                    float x = el[s * H + h] + erh[h];
                    x = (x > 0.0f) ? x : (NEGS * x);
                    s_alpha[lane * H + h] = __expf(x - m[h]) * inv[h];
                }
            }
            __syncthreads();
            int cnt = min(64, end - chunk);
            if (lane < NV) {
                for (int t = 0; t < cnt; ++t) {
                    const float4 v = *reinterpret_cast<const float4*>(
                        feat + (size_t)s_src[t] * HD + lane * 4);
                    float a = s_alpha[t * H + hc];
                    acc.x += a * v.x; acc.y += a * v.y;
                    acc.z += a * v.z; acc.w += a * v.w;
                }
            }
            __syncthreads();
        }
        if (lane < NV) {
            float4 v = acc;
            if (relu_mode == 2) {
                const float4 rv = *reinterpret_cast<const float4*>(
                    res + (size_t)n * HD + lane * 4);
                v.x += rv.x; v.y += rv.y; v.z += rv.z; v.w += rv.w;
            }
            if (relu_mode) {
                v.x = fmaxf(v.x, 0.f); v.y = fmaxf(v.y, 0.f);
                v.z = fmaxf(v.z, 0.f); v.w = fmaxf(v.w, 0.f);
            }
            *reinterpret_cast<float4*>(out + (size_t)n * HD + lane * 4) = v;
        }
    } else {
        constexpr int SLOTS = (HD + 63) / 64;
        float acc[SLOTS];
        #pragma unroll
        for (int r = 0; r < SLOTS; ++r) acc[r] = 0.0f;
        for (int chunk = beg; chunk < end; chunk += 64) {
            int j = chunk + lane;
            if (j < end) {
                int s = csr_src[j];
                s_src[lane] = s;
                #pragma unroll
                for (int h = 0; h < H; ++h) {
                    float x = el[s * H + h] + erh[h];
                    x = (x > 0.0f) ? x : (NEGS * x);
                    s_alpha[lane * H + h] = __expf(x - m[h]) * inv[h];
                }
            }
            __syncthreads();
            int cnt = min(64, end - chunk);
            for (int t = 0; t < cnt; ++t) {
                const float* fr = feat + (size_t)s_src[t] * HD;
                #pragma unroll
                for (int r = 0; r < SLOTS; ++r) {
                    int hd = r * 64 + lane;
                    if (hd < HD)
                        acc[r] += s_alpha[t * H + hd / D] * fr[hd];
                }
            }
            __syncthreads();
        }
        #pragma unroll
        for (int r = 0; r < SLOTS; ++r) {
            int hd = r * 64 + lane;
            if (hd < HD) {
                float v = acc[r];
                if (relu_mode == 2) v += res[(size_t)n * HD + hd];
                if (relu_mode) v = fmaxf(v, 0.0f);
                out[(size_t)n * HD + hd] = v;
            }
        }
    }
}

// ---------------- residual: res = norm_dst * sum_in(rawn[src]), float4 ----
__global__ void k_res_gather4(const int* __restrict__ rowptr, const int* __restrict__ csr_src,
                              const float* __restrict__ rawn, const float* __restrict__ norm,
                              float* __restrict__ res, int N) {
    constexpr int M4 = 40;
    int i = blockIdx.x * blockDim.x + threadIdx.x;
    if (i >= N * M4) return;
    int n = i / M4, q = i - n * M4;
    int beg = rowptr[n], end = rowptr[n + 1];
    float4 acc = make_float4(0.f, 0.f, 0.f, 0.f);
    for (int j = beg; j < end; ++j) {
        const float4 v = *reinterpret_cast<const float4*>(
            rawn + (size_t)csr_src[j] * 160 + q * 4);
        acc.x += v.x; acc.y += v.y; acc.z += v.z; acc.w += v.w;
    }
    float sc = norm[n];
    acc.x *= sc; acc.y *= sc; acc.z *= sc; acc.w *= sc;
    *reinterpret_cast<float4*>(res + (size_t)n * 160 + q * 4) = acc;
}

// ---------------- launch ----------------
extern "C" void kernel_launch(void* const* d_in, const int* in_sizes, int n_in,
                              void* d_out, int out_size, void* d_ws, size_t ws_size,
                              hipStream_t stream) {
    const float* features = (const float*)d_in[0];
    const int*   src      = (const int*)d_in[1];
    const int*   dst      = (const int*)d_in[2];
    const float* W0   = (const float*)d_in[3];
    const float* al0  = (const float*)d_in[4];
    const float* ar0  = (const float*)d_in[5];
    const float* W1   = (const float*)d_in[6];
    const float* al1  = (const float*)d_in[7];
    const float* ar1  = (const float*)d_in[8];
    const float* W2   = (const float*)d_in[9];
    const float* al2  = (const float*)d_in[10];
    const float* ar2  = (const float*)d_in[11];
    const float* Wout = (const float*)d_in[12];
    const float* alout= (const float*)d_in[13];
    const float* arout= (const float*)d_in[14];
    const float* Wraw = (const float*)d_in[15];
    const float* braw = (const float*)d_in[16];

    const int IN = 300, H = 5, D = 32, HD = 160, OUT = 10;
    const int N = in_sizes[0] / IN;   // 50000
    const int E = in_sizes[1];        // 800000

    char* w = (char*)d_ws;
    auto take = [&](size_t bytes) { char* r = w; w += (bytes + 255) & ~size_t(255); return r; };
    int*   deg     = (int*)  take((size_t)N * 4);
    int*   cnt     = (int*)  take((size_t)N * 4);
    int*   rowptr  = (int*)  take((size_t)(N + 1) * 4);
    int*   csr_src = (int*)  take((size_t)E * 4);
    float* norm    = (float*)take((size_t)N * 4);
    float* res     = (float*)take((size_t)N * HD * 4);
    float* rawn    = (float*)take((size_t)N * HD * 4);
    float* hbuf    = (float*)take((size_t)N * HD * 4);
    float* feat    = (float*)take((size_t)N * HD * 4);
    float* el      = (float*)take((size_t)N * H * 4);
    float* er      = (float*)take((size_t)N * H * 4);
    float* out = (float*)d_out;

    auto cdiv = [](long long a, long long b) { return (int)((a + b - 1) / b); };

    // 1. CSR build + norm
    hipMemsetAsync(deg, 0, (size_t)N * 4, stream);
    hipMemsetAsync(cnt, 0, (size_t)N * 4, stream);
    k_degi<<<cdiv(E, 256), 256, 0, stream>>>(dst, deg, E);
    k_scan<<<1, 1024, 0, stream>>>(deg, rowptr, norm, N);
    k_fill<<<cdiv(E, 256), 256, 0, stream>>>(src, dst, rowptr, cnt, csr_src, E);

    // 2. rawn = (features @ Wraw + braw) * norm
    k_gemm160<<<cdiv(N, 32), 320, 0, stream>>>(features, Wraw, braw, norm, rawn, N, IN);

    // 3. res = norm * gather_sum(rawn[src])
    k_res_gather4<<<cdiv((long long)N * 40, 256), 256, 0, stream>>>(rowptr, csr_src, rawn, norm, res, N);

    // 4. three GAT layers
    const float* x = features; int K = IN;
    const float* Ws[3]  = {W0, W1, W2};
    const float* als[3] = {al0, al1, al2};
    const float* ars[3] = {ar0, ar1, ar2};
    for (int L = 0; L < 3; L++) {
        k_gemm160<<<cdiv(N, 32), 320, 0, stream>>>(x, Ws[L], nullptr, nullptr, feat, N, K);
        k_elr32<<<cdiv((long long)N * H, 256), 256, 0, stream>>>(feat, als[L], ars[L], el, er, N, H);
        k_gat_fused<5, 32><<<N, 64, 0, stream>>>(rowptr, csr_src, el, er, feat, res, hbuf,
                                                 (L == 0) ? 1 : 2);
        x = hbuf; K = HD;
    }

    // 5. output GAT (H=1, D=OUT); mean over 1 head == identity
    k_gemv10<<<cdiv(N, 256), 256, 0, stream>>>(hbuf, Wout, feat, N, HD);
    k_elr_gen<<<cdiv(N, 256), 256, 0, stream>>>(feat, alout, arout, el, er, N, 1, OUT);
    k_gat_fused<1, 10><<<N, 64, 0, stream>>>(rowptr, csr_src, el, er, feat, nullptr, out, 0);
}

// Round 8
// 1078.780 us; speedup vs baseline: 1.2550x; 1.2550x over previous
//
#include <hip/hip_runtime.h>
#include <hip/hip_bf16.h>

#define NEGS 0.2f

typedef __attribute__((ext_vector_type(8))) short bf16x8;
typedef __attribute__((ext_vector_type(4))) float f32x4;

__device__ inline unsigned short bf16_rne(float x) {
    unsigned u = __float_as_uint(x);
    unsigned r = u + 0x7FFFu + ((u >> 16) & 1u);
    return (unsigned short)(r >> 16);
}

// ---------------- CSR build ----------------
__global__ void k_degi(const int* __restrict__ dst, int* __restrict__ deg, int E) {
    int e = blockIdx.x * blockDim.x + threadIdx.x;
    if (e < E) atomicAdd(&deg[dst[e]], 1);
}

__global__ __launch_bounds__(1024)
void k_scan(const int* __restrict__ deg, int* __restrict__ rowptr,
            float* __restrict__ norm, int N) {
    __shared__ int ssum[1024];
    int t = threadIdx.x;
    int chunk = (N + 1023) >> 10;
    int b = min(t * chunk, N), e = min(b + chunk, N);
    int s = 0;
    for (int i = b; i < e; ++i) s += deg[i];
    ssum[t] = s;
    __syncthreads();
    for (int off = 1; off < 1024; off <<= 1) {
        int v = (t >= off) ? ssum[t - off] : 0;
        __syncthreads();
        ssum[t] += v;
        __syncthreads();
    }
    int run = (t == 0) ? 0 : ssum[t - 1];
    for (int i = b; i < e; ++i) { rowptr[i] = run; run += deg[i]; }
    if (t == 0) rowptr[N] = ssum[1023];
    for (int i = b; i < e; ++i) norm[i] = rsqrtf(fmaxf((float)deg[i], 1.0f));
}

__global__ void k_fill(const int* __restrict__ src, const int* __restrict__ dst,
                       const int* __restrict__ rowptr, int* __restrict__ cnt,
                       int* __restrict__ csr_src, int E) {
    int e = blockIdx.x * blockDim.x + threadIdx.x;
    if (e >= E) return;
    int d = dst[e];
    int pos = rowptr[d] + atomicAdd(&cnt[d], 1);
    csr_src[pos] = src[e];
}

// ---------------- bf16 hi/lo split: X[N][K] -> hi/lo [N][KP] (zero-pad) ----
__global__ void k_splitX(const float* __restrict__ X, unsigned short* __restrict__ hi,
                         unsigned short* __restrict__ lo, int Nr, int K, int KP) {
    int i = blockIdx.x * blockDim.x + threadIdx.x;
    if (i >= Nr * KP) return;
    int n = i / KP, k = i - n * KP;
    float x = (k < K) ? X[(size_t)n * K + k] : 0.0f;
    unsigned short h = bf16_rne(x);
    float hf = __uint_as_float((unsigned)h << 16);
    hi[i] = h;
    lo[i] = bf16_rne(x - hf);
}

// W[K][160] -> WT hi/lo [160][KP] (zero-pad)
__global__ void k_splitWT(const float* __restrict__ W, unsigned short* __restrict__ hi,
                          unsigned short* __restrict__ lo, int K, int KP) {
    int i = blockIdx.x * blockDim.x + threadIdx.x;
    if (i >= 160 * KP) return;
    int c = i / KP, k = i - c * KP;
    float x = (k < K) ? W[(size_t)k * 160 + c] : 0.0f;
    unsigned short h = bf16_rne(x);
    float hf = __uint_as_float((unsigned)h << 16);
    hi[i] = h;
    lo[i] = bf16_rne(x - hf);
}

// ---------------- MFMA GEMM: C[N,160] = X[N,KP] @ W[KP,160] (bf16x3) ------
// One wave per 16-row strip; 10 col-tiles of 16; no LDS, no barriers.
// A-frag: lane l <- X[l&15][8*(l>>4)+j] (contig 16B). B-frag from WT rows.
// C/D: col = l&15, row = (l>>4)*4 + reg.
template<int NT>   // KP = NT*32
__global__ __launch_bounds__(256)
void k_gemm_mfma(const unsigned short* __restrict__ Xhi, const unsigned short* __restrict__ Xlo,
                 const unsigned short* __restrict__ WThi, const unsigned short* __restrict__ WTlo,
                 const float* __restrict__ bias, const float* __restrict__ rowscale,
                 float* __restrict__ C, int Nrows) {
    constexpr int KP = NT * 32;
    const int lane = threadIdx.x & 63;
    const int wave = threadIdx.x >> 6;
    const int row0 = blockIdx.x * 64 + wave * 16;
    const int lr = lane & 15;
    const int lq = lane >> 4;

    int arow = row0 + lr;
    int arow_c = (arow < Nrows) ? arow : (Nrows - 1);
    const unsigned short* pah = Xhi + (size_t)arow_c * KP + lq * 8;
    const unsigned short* pal = Xlo + (size_t)arow_c * KP + lq * 8;

    f32x4 acc[10] = {};
    for (int kt = 0; kt < NT; ++kt) {
        bf16x8 ah = *(const bf16x8*)(pah + kt * 32);
        bf16x8 al = *(const bf16x8*)(pal + kt * 32);
        #pragma unroll
        for (int ct = 0; ct < 10; ++ct) {
            const unsigned short* pbh = WThi + (size_t)(ct * 16 + lr) * KP + kt * 32 + lq * 8;
            const unsigned short* pbl = WTlo + (size_t)(ct * 16 + lr) * KP + kt * 32 + lq * 8;
            bf16x8 bh = *(const bf16x8*)pbh;
            bf16x8 bl = *(const bf16x8*)pbl;
            acc[ct] = __builtin_amdgcn_mfma_f32_16x16x32_bf16(ah, bh, acc[ct], 0, 0, 0);
            acc[ct] = __builtin_amdgcn_mfma_f32_16x16x32_bf16(ah, bl, acc[ct], 0, 0, 0);
            acc[ct] = __builtin_amdgcn_mfma_f32_16x16x32_bf16(al, bh, acc[ct], 0, 0, 0);
        }
    }
    #pragma unroll
    for (int i = 0; i < 4; ++i) {
        int row = row0 + lq * 4 + i;
        if (row >= Nrows) continue;
        float sc = rowscale ? rowscale[row] : 1.0f;
        #pragma unroll
        for (int ct = 0; ct < 10; ++ct) {
            int col = ct * 16 + lr;
            float v = acc[ct][i];
            if (bias) v += bias[col];
            C[(size_t)row * 160 + col] = v * sc;
        }
    }
}

// ---------------- small GEMM for Wout ----------------
__global__ __launch_bounds__(256)
void k_gemv10(const float* __restrict__ A, const float* __restrict__ B,
              float* __restrict__ C, int Nrows, int K) {
    __shared__ float Bs[160 * 10];
    for (int i = threadIdx.x; i < K * 10; i += 256) Bs[i] = B[i];
    __syncthreads();
    int row = blockIdx.x * 256 + threadIdx.x;
    if (row >= Nrows) return;
    float acc[10] = {};
    const float4* a = reinterpret_cast<const float4*>(A + (size_t)row * K);
    for (int kq = 0; kq < K / 4; ++kq) {
        float4 v = a[kq];
        int k = kq * 4;
        #pragma unroll
        for (int j = 0; j < 10; ++j)
            acc[j] += v.x * Bs[(k + 0) * 10 + j] + v.y * Bs[(k + 1) * 10 + j]
                    + v.z * Bs[(k + 2) * 10 + j] + v.w * Bs[(k + 3) * 10 + j];
    }
    #pragma unroll
    for (int j = 0; j < 10; ++j) C[(size_t)row * 10 + j] = acc[j];
}

// ---------------- attention logits el/er ----------------
__global__ void k_elr32(const float* __restrict__ feat, const float* __restrict__ al,
                        const float* __restrict__ ar, float* __restrict__ el,
                        float* __restrict__ er, int N, int H) {
    int i = blockIdx.x * blockDim.x + threadIdx.x;
    if (i >= N * H) return;
    int h = i % H;
    const float4* f = (const float4*)(feat + (size_t)i * 32);
    const float4* a = (const float4*)(al + h * 32);
    const float4* b = (const float4*)(ar + h * 32);
    float sl = 0.0f, sr = 0.0f;
    #pragma unroll
    for (int d = 0; d < 8; d++) {
        float4 v = f[d], x = a[d], y = b[d];
        sl += v.x * x.x + v.y * x.y + v.z * x.z + v.w * x.w;
        sr += v.x * y.x + v.y * y.y + v.z * y.z + v.w * y.w;
    }
    el[i] = sl; er[i] = sr;
}

__global__ void k_elr_gen(const float* __restrict__ feat, const float* __restrict__ al,
                          const float* __restrict__ ar, float* __restrict__ el,
                          float* __restrict__ er, int N, int H, int D) {
    int i = blockIdx.x * blockDim.x + threadIdx.x;
    if (i >= N * H) return;
    int h = i % H;
    const float* f = feat + (size_t)i * D;
    const float* a = al + h * D;
    const float* b = ar + h * D;
    float sl = 0.0f, sr = 0.0f;
    for (int d = 0; d < D; d++) { float v = f[d]; sl += v * a[d]; sr += v * b[d]; }
    el[i] = sl; er[i] = sr;
}

// ---------------- fused GAT: online softmax + float4 weighted gather ----
// relu_mode: 0 none, 1 relu, 2 add res then relu. ohi/olo: optional bf16 split out.
template<int H, int D>
__global__ __launch_bounds__(64)
void k_gat_fused(const int* __restrict__ rowptr, const int* __restrict__ csr_src,
                 const float* __restrict__ el, const float* __restrict__ er,
                 const float* __restrict__ feat, const float* __restrict__ res,
                 float* __restrict__ out, unsigned short* __restrict__ ohi,
                 unsigned short* __restrict__ olo, int relu_mode) {
    constexpr int HD = H * D;
    const int n = blockIdx.x;
    const int lane = threadIdx.x;
    const int beg = rowptr[n], end = rowptr[n + 1];

    float erh[H];
    #pragma unroll
    for (int h = 0; h < H; ++h) erh[h] = er[n * H + h];

    float m[H], ssum[H];
    #pragma unroll
    for (int h = 0; h < H; ++h) { m[h] = -1e30f; ssum[h] = 0.0f; }
    for (int j = beg + lane; j < end; j += 64) {
        int s = csr_src[j];
        #pragma unroll
        for (int h = 0; h < H; ++h) {
            float x = el[s * H + h] + erh[h];
            x = (x > 0.0f) ? x : (NEGS * x);
            float mn = fmaxf(m[h], x);
            ssum[h] = ssum[h] * __expf(m[h] - mn) + __expf(x - mn);
            m[h] = mn;
        }
    }
    float inv[H];
    #pragma unroll
    for (int h = 0; h < H; ++h) {
        #pragma unroll
        for (int off = 32; off; off >>= 1) {
            float mo = __shfl_xor(m[h], off, 64);
            float so = __shfl_xor(ssum[h], off, 64);
            float mn = fmaxf(m[h], mo);
            ssum[h] = ssum[h] * __expf(m[h] - mn) + so * __expf(mo - mn);
            m[h] = mn;
        }
        inv[h] = (ssum[h] > 0.0f) ? 1.0f / ssum[h] : 0.0f;
    }

    __shared__ float s_alpha[64 * H];
    __shared__ int   s_src[64];

    if constexpr ((D & 3) == 0) {
        constexpr int NV = HD / 4;
        const int hc = (lane * 4) / D;
        float4 acc = make_float4(0.f, 0.f, 0.f, 0.f);
        for (int chunk = beg; chunk < end; chunk += 64) {
            int j = chunk + lane;
            if (j < end) {
                int s = csr_src[j];
                s_src[lane] = s;
                #pragma unroll
                for (int h = 0; h < H; ++h) {
                    float x = el[s * H + h] + erh[h];
                    x = (x > 0.0f) ? x : (NEGS * x);
                    s_alpha[lane * H + h] = __expf(x - m[h]) * inv[h];
                }
            }
            __syncthreads();
            int cnt = min(64, end - chunk);
            if (lane < NV) {
                for (int t = 0; t < cnt; ++t) {
                    const float4 v = *reinterpret_cast<const float4*>(
                        feat + (size_t)s_src[t] * HD + lane * 4);
                    float a = s_alpha[t * H + hc];
                    acc.x += a * v.x; acc.y += a * v.y;
                    acc.z += a * v.z; acc.w += a * v.w;
                }
            }
            __syncthreads();
        }
        if (lane < NV) {
            float4 v = acc;
            if (relu_mode == 2) {
                const float4 rv = *reinterpret_cast<const float4*>(
                    res + (size_t)n * HD + lane * 4);
                v.x += rv.x; v.y += rv.y; v.z += rv.z; v.w += rv.w;
            }
            if (relu_mode) {
                v.x = fmaxf(v.x, 0.f); v.y = fmaxf(v.y, 0.f);
                v.z = fmaxf(v.z, 0.f); v.w = fmaxf(v.w, 0.f);
            }
            *reinterpret_cast<float4*>(out + (size_t)n * HD + lane * 4) = v;
            if (ohi) {
                ushort4 hv, lv;
                float c[4] = {v.x, v.y, v.z, v.w};
                unsigned short hh[4], ll[4];
                #pragma unroll
                for (int e2 = 0; e2 < 4; ++e2) {
                    hh[e2] = bf16_rne(c[e2]);
                    float hf = __uint_as_float((unsigned)hh[e2] << 16);
                    ll[e2] = bf16_rne(c[e2] - hf);
                }
                hv.x = hh[0]; hv.y = hh[1]; hv.z = hh[2]; hv.w = hh[3];
                lv.x = ll[0]; lv.y = ll[1]; lv.z = ll[2]; lv.w = ll[3];
                *reinterpret_cast<ushort4*>(ohi + (size_t)n * HD + lane * 4) = hv;
                *reinterpret_cast<ushort4*>(olo + (size_t)n * HD + lane * 4) = lv;
            }
        }
    } else {
        constexpr int SLOTS = (HD + 63) / 64;
        float acc[SLOTS];
        #pragma unroll
        for (int r = 0; r < SLOTS; ++r) acc[r] = 0.0f;
        for (int chunk = beg; chunk < end; chunk += 64) {
            int j = chunk + lane;
            if (j < end) {
                int s = csr_src[j];
                s_src[lane] = s;
                #pragma unroll
                for (int h = 0; h < H; ++h) {
                    float x = el[s * H + h] + erh[h];
                    x = (x > 0.0f) ? x : (NEGS * x);
                    s_alpha[lane * H + h] = __expf(x - m[h]) * inv[h];
                }
            }
            __syncthreads();
            int cnt = min(64, end - chunk);
            for (int t = 0; t < cnt; ++t) {
                const float* fr = feat + (size_t)s_src[t] * HD;
                #pragma unroll
                for (int r = 0; r < SLOTS; ++r) {
                    int hd = r * 64 + lane;
                    if (hd < HD)
                        acc[r] += s_alpha[t * H + hd / D] * fr[hd];
                }
            }
            __syncthreads();
        }
        #pragma unroll
        for (int r = 0; r < SLOTS; ++r) {
            int hd = r * 64 + lane;
            if (hd < HD) {
                float v = acc[r];
                if (relu_mode == 2) v += res[(size_t)n * HD + hd];
                if (relu_mode) v = fmaxf(v, 0.0f);
                out[(size_t)n * HD + hd] = v;
            }
        }
    }
}

// ---------------- residual: res = norm_dst * sum_in(rawn[src]), float4 ----
__global__ void k_res_gather4(const int* __restrict__ rowptr, const int* __restrict__ csr_src,
                              const float* __restrict__ rawn, const float* __restrict__ norm,
                              float* __restrict__ res, int N) {
    constexpr int M4 = 40;
    int i = blockIdx.x * blockDim.x + threadIdx.x;
    if (i >= N * M4) return;
    int n = i / M4, q = i - n * M4;
    int beg = rowptr[n], end = rowptr[n + 1];
    float4 acc = make_float4(0.f, 0.f, 0.f, 0.f);
    for (int j = beg; j < end; ++j) {
        const float4 v = *reinterpret_cast<const float4*>(
            rawn + (size_t)csr_src[j] * 160 + q * 4);
        acc.x += v.x; acc.y += v.y; acc.z += v.z; acc.w += v.w;
    }
    float sc = norm[n];
    acc.x *= sc; acc.y *= sc; acc.z *= sc; acc.w *= sc;
    *reinterpret_cast<float4*>(res + (size_t)n * 160 + q * 4) = acc;
}

// ---------------- launch ----------------
extern "C" void kernel_launch(void* const* d_in, const int* in_sizes, int n_in,
                              void* d_out, int out_size, void* d_ws, size_t ws_size,
                              hipStream_t stream) {
    const float* features = (const float*)d_in[0];
    const int*   src      = (const int*)d_in[1];
    const int*   dst      = (const int*)d_in[2];
    const float* W0   = (const float*)d_in[3];
    const float* al0  = (const float*)d_in[4];
    const float* ar0  = (const float*)d_in[5];
    const float* W1   = (const float*)d_in[6];
    const float* al1  = (const float*)d_in[7];
    const float* ar1  = (const float*)d_in[8];
    const float* W2   = (const float*)d_in[9];
    const float* al2  = (const float*)d_in[10];
    const float* ar2  = (const float*)d_in[11];
    const float* Wout = (const float*)d_in[12];
    const float* alout= (const float*)d_in[13];
    const float* arout= (const float*)d_in[14];
    const float* Wraw = (const float*)d_in[15];
    const float* braw = (const float*)d_in[16];

    const int IN = 300, INP = 320, H = 5, D = 32, HD = 160, OUT = 10;
    const int N = in_sizes[0] / IN;   // 50000
    const int E = in_sizes[1];        // 800000

    char* w = (char*)d_ws;
    auto take = [&](size_t bytes) { char* r = w; w += (bytes + 255) & ~size_t(255); return r; };
    int*   deg     = (int*)  take((size_t)N * 4);
    int*   cnt     = (int*)  take((size_t)N * 4);
    int*   rowptr  = (int*)  take((size_t)(N + 1) * 4);
    int*   csr_src = (int*)  take((size_t)E * 4);
    float* norm    = (float*)take((size_t)N * 4);
    float* el      = (float*)take((size_t)N * H * 4);
    float* er      = (float*)take((size_t)N * H * 4);
    float* res     = (float*)take((size_t)N * HD * 4);
    float* featP   = (float*)take((size_t)N * HD * 4);   // rawn, then per-layer projection
    float* hbuf    = (float*)take((size_t)N * HD * 4);   // gat output fp32 (overwritten per layer)
    unsigned short* fhi = (unsigned short*)take((size_t)N * INP * 2);  // later: hAhi+hAlo
    unsigned short* flo = (unsigned short*)take((size_t)N * INP * 2);  // later: hBhi+hBlo
    unsigned short* wrh = (unsigned short*)take((size_t)160 * INP * 2);
    unsigned short* wrl = (unsigned short*)take((size_t)160 * INP * 2);
    unsigned short* w0h = (unsigned short*)take((size_t)160 * INP * 2);
    unsigned short* w0l = (unsigned short*)take((size_t)160 * INP * 2);
    unsigned short* w1h = (unsigned short*)take((size_t)160 * HD * 2);
    unsigned short* w1l = (unsigned short*)take((size_t)160 * HD * 2);
    unsigned short* w2h = (unsigned short*)take((size_t)160 * HD * 2);
    unsigned short* w2l = (unsigned short*)take((size_t)160 * HD * 2);
    float* out = (float*)d_out;

    // aliases into fhi/flo regions after those are dead (post layer-0 GEMM)
    unsigned short* hAhi = fhi;
    unsigned short* hAlo = fhi + (size_t)N * HD;
    unsigned short* hBhi = flo;
    unsigned short* hBlo = flo + (size_t)N * HD;

    auto cdiv = [](long long a, long long b) { return (int)((a + b - 1) / b); };

    // 1. CSR build + norm
    hipMemsetAsync(deg, 0, (size_t)N * 4, stream);
    hipMemsetAsync(cnt, 0, (size_t)N * 4, stream);
    k_degi<<<cdiv(E, 256), 256, 0, stream>>>(dst, deg, E);
    k_scan<<<1, 1024, 0, stream>>>(deg, rowptr, norm, N);
    k_fill<<<cdiv(E, 256), 256, 0, stream>>>(src, dst, rowptr, cnt, csr_src, E);

    // 2. weight transposes + splits, feature split
    k_splitWT<<<cdiv(160 * INP, 256), 256, 0, stream>>>(Wraw, wrh, wrl, IN, INP);
    k_splitWT<<<cdiv(160 * INP, 256), 256, 0, stream>>>(W0, w0h, w0l, IN, INP);
    k_splitWT<<<cdiv(160 * HD, 256), 256, 0, stream>>>(W1, w1h, w1l, HD, HD);
    k_splitWT<<<cdiv(160 * HD, 256), 256, 0, stream>>>(W2, w2h, w2l, HD, HD);
    k_splitX<<<cdiv((long long)N * INP, 256), 256, 0, stream>>>(features, fhi, flo, N, IN, INP);

    // 3. rawn = (features @ Wraw + braw) * norm  -> featP
    k_gemm_mfma<10><<<cdiv(N, 64), 256, 0, stream>>>(fhi, flo, wrh, wrl, braw, norm, featP, N);

    // 4. res = norm * gather_sum(rawn[src])
    k_res_gather4<<<cdiv((long long)N * 40, 256), 256, 0, stream>>>(rowptr, csr_src, featP, norm, res, N);

    // 5. layer 0 (K=300 padded 320)
    k_gemm_mfma<10><<<cdiv(N, 64), 256, 0, stream>>>(fhi, flo, w0h, w0l, nullptr, nullptr, featP, N);
    k_elr32<<<cdiv((long long)N * H, 256), 256, 0, stream>>>(featP, al0, ar0, el, er, N, H);
    k_gat_fused<5, 32><<<N, 64, 0, stream>>>(rowptr, csr_src, el, er, featP, nullptr,
                                             hbuf, hAhi, hAlo, 1);

    // 6. layer 1 (K=160)
    k_gemm_mfma<5><<<cdiv(N, 64), 256, 0, stream>>>(hAhi, hAlo, w1h, w1l, nullptr, nullptr, featP, N);
    k_elr32<<<cdiv((long long)N * H, 256), 256, 0, stream>>>(featP, al1, ar1, el, er, N, H);
    k_gat_fused<5, 32><<<N, 64, 0, stream>>>(rowptr, csr_src, el, er, featP, res,
                                             hbuf, hBhi, hBlo, 2);

    // 7. layer 2 (K=160)
    k_gemm_mfma<5><<<cdiv(N, 64), 256, 0, stream>>>(hBhi, hBlo, w2h, w2l, nullptr, nullptr, featP, N);
    k_elr32<<<cdiv((long long)N * H, 256), 256, 0, stream>>>(featP, al2, ar2, el, er, N, H);
    k_gat_fused<5, 32><<<N, 64, 0, stream>>>(rowptr, csr_src, el, er, featP, res,
                                             hbuf, nullptr, nullptr, 2);

    // 8. output GAT (H=1, D=OUT); mean over 1 head == identity
    k_gemv10<<<cdiv(N, 256), 256, 0, stream>>>(hbuf, Wout, featP, N, HD);
    k_elr_gen<<<cdiv(N, 256), 256, 0, stream>>>(featP, alout, arout, el, er, N, 1, OUT);
    k_gat_fused<1, 10><<<N, 64, 0, stream>>>(rowptr, csr_src, el, er, featP, nullptr,
                                             out, nullptr, nullptr, 0);
}

// Round 9
// 959.141 us; speedup vs baseline: 1.4116x; 1.1247x over previous
//
#include <hip/hip_runtime.h>
#include <hip/hip_bf16.h>

#define NEGS 0.2f

typedef __attribute__((ext_vector_type(8))) short bf16x8;
typedef __attribute__((ext_vector_type(4))) float f32x4;

__device__ inline unsigned short bf16_rne(float x) {
    unsigned u = __float_as_uint(x);
    unsigned r = u + 0x7FFFu + ((u >> 16) & 1u);
    return (unsigned short)(r >> 16);
}

// ---------------- CSR build ----------------
__global__ void k_degi(const int* __restrict__ dst, int* __restrict__ deg, int E) {
    int e = blockIdx.x * blockDim.x + threadIdx.x;
    if (e < E) atomicAdd(&deg[dst[e]], 1);
}

// phase 1: in-block exclusive scan of deg + norm
__global__ __launch_bounds__(256)
void k_scan1(const int* __restrict__ deg, int* __restrict__ rowptr,
             int* __restrict__ bsum, float* __restrict__ norm, int N) {
    __shared__ int sdata[256];
    int t = threadIdx.x, i = blockIdx.x * 256 + t;
    int d = (i < N) ? deg[i] : 0;
    sdata[t] = d;
    __syncthreads();
    for (int off = 1; off < 256; off <<= 1) {
        int v = (t >= off) ? sdata[t - off] : 0;
        __syncthreads();
        sdata[t] += v;
        __syncthreads();
    }
    if (i < N) {
        rowptr[i] = sdata[t] - d;            // exclusive within block
        norm[i] = rsqrtf(fmaxf((float)d, 1.0f));
    }
    if (t == 255) bsum[blockIdx.x] = sdata[255];
}

// phase 2: scan block sums (nb <= 256), write grand total to rowptrN
__global__ __launch_bounds__(256)
void k_scan2(const int* __restrict__ bsum, int* __restrict__ boff,
             int* __restrict__ rowptrN, int nb) {
    __shared__ int sdata[256];
    int t = threadIdx.x;
    int v = (t < nb) ? bsum[t] : 0;
    sdata[t] = v;
    __syncthreads();
    for (int off = 1; off < 256; off <<= 1) {
        int x = (t >= off) ? sdata[t - off] : 0;
        __syncthreads();
        sdata[t] += x;
        __syncthreads();
    }
    if (t < nb) boff[t] = sdata[t] - v;
    if (t == 255) *rowptrN = sdata[255];
}

// phase 3: add block offsets
__global__ __launch_bounds__(256)
void k_scan3(int* __restrict__ rowptr, const int* __restrict__ boff, int N) {
    int i = blockIdx.x * 256 + threadIdx.x;
    if (i < N) rowptr[i] += boff[blockIdx.x];
}

__global__ void k_fill(const int* __restrict__ src, const int* __restrict__ dst,
                       const int* __restrict__ rowptr, int* __restrict__ cnt,
                       int* __restrict__ csr_src, int E) {
    int e = blockIdx.x * blockDim.x + threadIdx.x;
    if (e >= E) return;
    int d = dst[e];
    int pos = rowptr[d] + atomicAdd(&cnt[d], 1);
    csr_src[pos] = src[e];
}

// ---------------- bf16 hi/lo split ----------------
__global__ void k_splitX(const float* __restrict__ X, unsigned short* __restrict__ hi,
                         unsigned short* __restrict__ lo, int Nr, int K, int KP) {
    int i = blockIdx.x * blockDim.x + threadIdx.x;
    if (i >= Nr * KP) return;
    int n = i / KP, k = i - n * KP;
    float x = (k < K) ? X[(size_t)n * K + k] : 0.0f;
    unsigned short h = bf16_rne(x);
    float hf = __uint_as_float((unsigned)h << 16);
    hi[i] = h;
    lo[i] = bf16_rne(x - hf);
}

__global__ void k_splitWT(const float* __restrict__ W, unsigned short* __restrict__ hi,
                          unsigned short* __restrict__ lo, int K, int KP) {
    int i = blockIdx.x * blockDim.x + threadIdx.x;
    if (i >= 160 * KP) return;
    int c = i / KP, k = i - c * KP;
    float x = (k < K) ? W[(size_t)k * 160 + c] : 0.0f;
    unsigned short h = bf16_rne(x);
    float hf = __uint_as_float((unsigned)h << 16);
    hi[i] = h;
    lo[i] = bf16_rne(x - hf);
}

// ---------------- MFMA GEMM: C[N,160] = X[N,KP] @ W[KP,160] (bf16x3) ------
// One wave per 16-row strip. If al != nullptr, also emits el/er ([N][5])
// via in-register per-head reduction (fused k_elr).
template<int NT>   // KP = NT*32
__global__ __launch_bounds__(256)
void k_gemm_mfma(const unsigned short* __restrict__ Xhi, const unsigned short* __restrict__ Xlo,
                 const unsigned short* __restrict__ WThi, const unsigned short* __restrict__ WTlo,
                 const float* __restrict__ bias, const float* __restrict__ rowscale,
                 float* __restrict__ C, int Nrows,
                 const float* __restrict__ al, const float* __restrict__ ar,
                 float* __restrict__ el, float* __restrict__ er) {
    constexpr int KP = NT * 32;
    const int lane = threadIdx.x & 63;
    const int wave = threadIdx.x >> 6;
    const int row0 = blockIdx.x * 64 + wave * 16;
    const int lr = lane & 15;
    const int lq = lane >> 4;

    int arow = row0 + lr;
    int arow_c = (arow < Nrows) ? arow : (Nrows - 1);
    const unsigned short* pah = Xhi + (size_t)arow_c * KP + lq * 8;
    const unsigned short* pal = Xlo + (size_t)arow_c * KP + lq * 8;

    f32x4 acc[10] = {};
    for (int kt = 0; kt < NT; ++kt) {
        bf16x8 ah = *(const bf16x8*)(pah + kt * 32);
        bf16x8 al8 = *(const bf16x8*)(pal + kt * 32);
        #pragma unroll
        for (int ct = 0; ct < 10; ++ct) {
            const unsigned short* pbh = WThi + (size_t)(ct * 16 + lr) * KP + kt * 32 + lq * 8;
            const unsigned short* pbl = WTlo + (size_t)(ct * 16 + lr) * KP + kt * 32 + lq * 8;
            bf16x8 bh = *(const bf16x8*)pbh;
            bf16x8 bl = *(const bf16x8*)pbl;
            acc[ct] = __builtin_amdgcn_mfma_f32_16x16x32_bf16(ah, bh, acc[ct], 0, 0, 0);
            acc[ct] = __builtin_amdgcn_mfma_f32_16x16x32_bf16(ah, bl, acc[ct], 0, 0, 0);
            acc[ct] = __builtin_amdgcn_mfma_f32_16x16x32_bf16(al8, bh, acc[ct], 0, 0, 0);
        }
    }

    // C write (+bias/+rowscale)
    #pragma unroll
    for (int i = 0; i < 4; ++i) {
        int row = row0 + lq * 4 + i;
        if (row >= Nrows) continue;
        float sc = rowscale ? rowscale[row] : 1.0f;
        #pragma unroll
        for (int ct = 0; ct < 10; ++ct) {
            int col = ct * 16 + lr;
            float v = acc[ct][i];
            if (bias) v += bias[col];
            C[(size_t)row * 160 + col] = v * sc;
        }
    }

    // fused el/er: el[row][h] = sum_d feat[row][h*32+d]*al[h][d]
    if (al) {
        float alv0[5], alv1[5], arv0[5], arv1[5];
        #pragma unroll
        for (int h = 0; h < 5; ++h) {
            alv0[h] = al[h * 32 + lr]; alv1[h] = al[h * 32 + 16 + lr];
            arv0[h] = ar[h * 32 + lr]; arv1[h] = ar[h * 32 + 16 + lr];
        }
        #pragma unroll
        for (int i = 0; i < 4; ++i) {
            int row = row0 + lq * 4 + i;
            #pragma unroll
            for (int h = 0; h < 5; ++h) {
                float e_l = acc[2 * h][i] * alv0[h] + acc[2 * h + 1][i] * alv1[h];
                float e_r = acc[2 * h][i] * arv0[h] + acc[2 * h + 1][i] * arv1[h];
                #pragma unroll
                for (int off2 = 8; off2; off2 >>= 1) {
                    e_l += __shfl_xor(e_l, off2, 64);
                    e_r += __shfl_xor(e_r, off2, 64);
                }
                if (lr == h && row < Nrows) {
                    el[row * 5 + h] = e_l;
                    er[row * 5 + h] = e_r;
                }
            }
        }
    }
}

// ---------------- small GEMM for Wout ----------------
__global__ __launch_bounds__(256)
void k_gemv10(const float* __restrict__ A, const float* __restrict__ B,
              float* __restrict__ C, int Nrows, int K) {
    __shared__ float Bs[160 * 10];
    for (int i = threadIdx.x; i < K * 10; i += 256) Bs[i] = B[i];
    __syncthreads();
    int row = blockIdx.x * 256 + threadIdx.x;
    if (row >= Nrows) return;
    float acc[10] = {};
    const float4* a = reinterpret_cast<const float4*>(A + (size_t)row * K);
    for (int kq = 0; kq < K / 4; ++kq) {
        float4 v = a[kq];
        int k = kq * 4;
        #pragma unroll
        for (int j = 0; j < 10; ++j)
            acc[j] += v.x * Bs[(k + 0) * 10 + j] + v.y * Bs[(k + 1) * 10 + j]
                    + v.z * Bs[(k + 2) * 10 + j] + v.w * Bs[(k + 3) * 10 + j];
    }
    #pragma unroll
    for (int j = 0; j < 10; ++j) C[(size_t)row * 10 + j] = acc[j];
}

// ---------------- el/er for output layer (H=1, D=10) ----------------
__global__ void k_elr_gen(const float* __restrict__ feat, const float* __restrict__ al,
                          const float* __restrict__ ar, float* __restrict__ el,
                          float* __restrict__ er, int N, int H, int D) {
    int i = blockIdx.x * blockDim.x + threadIdx.x;
    if (i >= N * H) return;
    int h = i % H;
    const float* f = feat + (size_t)i * D;
    const float* a = al + h * D;
    const float* b = ar + h * D;
    float sl = 0.0f, sr = 0.0f;
    for (int d = 0; d < D; d++) { float v = f[d]; sl += v * a[d]; sr += v * b[d]; }
    el[i] = sl; er[i] = sr;
}

// ---------------- fused GAT: online softmax + float4 weighted gather ----
template<int H, int D>
__global__ __launch_bounds__(64)
void k_gat_fused(const int* __restrict__ rowptr, const int* __restrict__ csr_src,
                 const float* __restrict__ el, const float* __restrict__ er,
                 const float* __restrict__ feat, const float* __restrict__ res,
                 float* __restrict__ out, unsigned short* __restrict__ ohi,
                 unsigned short* __restrict__ olo, int relu_mode) {
    constexpr int HD = H * D;
    const int n = blockIdx.x;
    const int lane = threadIdx.x;
    const int beg = rowptr[n], end = rowptr[n + 1];

    float erh[H];
    #pragma unroll
    for (int h = 0; h < H; ++h) erh[h] = er[n * H + h];

    float m[H], ssum[H];
    #pragma unroll
    for (int h = 0; h < H; ++h) { m[h] = -1e30f; ssum[h] = 0.0f; }
    for (int j = beg + lane; j < end; j += 64) {
        int s = csr_src[j];
        #pragma unroll
        for (int h = 0; h < H; ++h) {
            float x = el[s * H + h] + erh[h];
            x = (x > 0.0f) ? x : (NEGS * x);
            float mn = fmaxf(m[h], x);
            ssum[h] = ssum[h] * __expf(m[h] - mn) + __expf(x - mn);
            m[h] = mn;
        }
    }
    float inv[H];
    #pragma unroll
    for (int h = 0; h < H; ++h) {
        #pragma unroll
        for (int off = 32; off; off >>= 1) {
            float mo = __shfl_xor(m[h], off, 64);
            float so = __shfl_xor(ssum[h], off, 64);
            float mn = fmaxf(m[h], mo);
            ssum[h] = ssum[h] * __expf(m[h] - mn) + so * __expf(mo - mn);
            m[h] = mn;
        }
        inv[h] = (ssum[h] > 0.0f) ? 1.0f / ssum[h] : 0.0f;
    }

    __shared__ float s_alpha[64 * H];
    __shared__ int   s_src[64];

    if constexpr ((D & 3) == 0) {
        constexpr int NV = HD / 4;
        const int hc = (lane * 4) / D;
        float4 acc = make_float4(0.f, 0.f, 0.f, 0.f);
        for (int chunk = beg; chunk < end; chunk += 64) {
            int j = chunk + lane;
            if (j < end) {
                int s = csr_src[j];
                s_src[lane] = s;
                #pragma unroll
                for (int h = 0; h < H; ++h) {
                    float x = el[s * H + h] + erh[h];
                    x = (x > 0.0f) ? x : (NEGS * x);
                    s_alpha[lane * H + h] = __expf(x - m[h]) * inv[h];
                }
            }
            __syncthreads();
            int cnt = min(64, end - chunk);
            if (lane < NV) {
                for (int t = 0; t < cnt; ++t) {
                    const float4 v = *reinterpret_cast<const float4*>(
                        feat + (size_t)s_src[t] * HD + lane * 4);
                    float a = s_alpha[t * H + hc];
                    acc.x += a * v.x; acc.y += a * v.y;
                    acc.z += a * v.z; acc.w += a * v.w;
                }
            }
            __syncthreads();
        }
        if (lane < NV) {
            float4 v = acc;
            if (relu_mode == 2) {
                const float4 rv = *reinterpret_cast<const float4*>(
                    res + (size_t)n * HD + lane * 4);
                v.x += rv.x; v.y += rv.y; v.z += rv.z; v.w += rv.w;
            }
            if (relu_mode) {
                v.x = fmaxf(v.x, 0.f); v.y = fmaxf(v.y, 0.f);
                v.z = fmaxf(v.z, 0.f); v.w = fmaxf(v.w, 0.f);
            }
            *reinterpret_cast<float4*>(out + (size_t)n * HD + lane * 4) = v;
            if (ohi) {
                ushort4 hv, lv;
                float c[4] = {v.x, v.y, v.z, v.w};
                unsigned short hh[4], ll[4];
                #pragma unroll
                for (int e2 = 0; e2 < 4; ++e2) {
                    hh[e2] = bf16_rne(c[e2]);
                    float hf = __uint_as_float((unsigned)hh[e2] << 16);
                    ll[e2] = bf16_rne(c[e2] - hf);
                }
                hv.x = hh[0]; hv.y = hh[1]; hv.z = hh[2]; hv.w = hh[3];
                lv.x = ll[0]; lv.y = ll[1]; lv.z = ll[2]; lv.w = ll[3];
                *reinterpret_cast<ushort4*>(ohi + (size_t)n * HD + lane * 4) = hv;
                *reinterpret_cast<ushort4*>(olo + (size_t)n * HD + lane * 4) = lv;
            }
        }
    } else {
        constexpr int SLOTS = (HD + 63) / 64;
        float acc[SLOTS];
        #pragma unroll
        for (int r = 0; r < SLOTS; ++r) acc[r] = 0.0f;
        for (int chunk = beg; chunk < end; chunk += 64) {
            int j = chunk + lane;
            if (j < end) {
                int s = csr_src[j];
                s_src[lane] = s;
                #pragma unroll
                for (int h = 0; h < H; ++h) {
                    float x = el[s * H + h] + erh[h];
                    x = (x > 0.0f) ? x : (NEGS * x);
                    s_alpha[lane * H + h] = __expf(x - m[h]) * inv[h];
                }
            }
            __syncthreads();
            int cnt = min(64, end - chunk);
            for (int t = 0; t < cnt; ++t) {
                const float* fr = feat + (size_t)s_src[t] * HD;
                #pragma unroll
                for (int r = 0; r < SLOTS; ++r) {
                    int hd = r * 64 + lane;
                    if (hd < HD)
                        acc[r] += s_alpha[t * H + hd / D] * fr[hd];
                }
            }
            __syncthreads();
        }
        #pragma unroll
        for (int r = 0; r < SLOTS; ++r) {
            int hd = r * 64 + lane;
            if (hd < HD) {
                float v = acc[r];
                if (relu_mode == 2) v += res[(size_t)n * HD + hd];
                if (relu_mode) v = fmaxf(v, 0.0f);
                out[(size_t)n * HD + hd] = v;
            }
        }
    }
}

// ---------------- residual: res = norm_dst * sum_in(rawn[src]), float4 ----
__global__ void k_res_gather4(const int* __restrict__ rowptr, const int* __restrict__ csr_src,
                              const float* __restrict__ rawn, const float* __restrict__ norm,
                              float* __restrict__ res, int N) {
    constexpr int M4 = 40;
    int i = blockIdx.x * blockDim.x + threadIdx.x;
    if (i >= N * M4) return;
    int n = i / M4, q = i - n * M4;
    int beg = rowptr[n], end = rowptr[n + 1];
    float4 acc = make_float4(0.f, 0.f, 0.f, 0.f);
    for (int j = beg; j < end; ++j) {
        const float4 v = *reinterpret_cast<const float4*>(
            rawn + (size_t)csr_src[j] * 160 + q * 4);
        acc.x += v.x; acc.y += v.y; acc.z += v.z; acc.w += v.w;
    }
    float sc = norm[n];
    acc.x *= sc; acc.y *= sc; acc.z *= sc; acc.w *= sc;
    *reinterpret_cast<float4*>(res + (size_t)n * 160 + q * 4) = acc;
}

// ---------------- launch ----------------
extern "C" void kernel_launch(void* const* d_in, const int* in_sizes, int n_in,
                              void* d_out, int out_size, void* d_ws, size_t ws_size,
                              hipStream_t stream) {
    const float* features = (const float*)d_in[0];
    const int*   src      = (const int*)d_in[1];
    const int*   dst      = (const int*)d_in[2];
    const float* W0   = (const float*)d_in[3];
    const float* al0  = (const float*)d_in[4];
    const float* ar0  = (const float*)d_in[5];
    const float* W1   = (const float*)d_in[6];
    const float* al1  = (const float*)d_in[7];
    const float* ar1  = (const float*)d_in[8];
    const float* W2   = (const float*)d_in[9];
    const float* al2  = (const float*)d_in[10];
    const float* ar2  = (const float*)d_in[11];
    const float* Wout = (const float*)d_in[12];
    const float* alout= (const float*)d_in[13];
    const float* arout= (const float*)d_in[14];
    const float* Wraw = (const float*)d_in[15];
    const float* braw = (const float*)d_in[16];

    const int IN = 300, INP = 320, H = 5, D = 32, HD = 160, OUT = 10;
    const int N = in_sizes[0] / IN;   // 50000
    const int E = in_sizes[1];        // 800000

    char* w = (char*)d_ws;
    auto take = [&](size_t bytes) { char* r = w; w += (bytes + 255) & ~size_t(255); return r; };
    int*   deg     = (int*)  take((size_t)N * 4);
    int*   cnt     = (int*)  take((size_t)N * 4);
    int*   rowptr  = (int*)  take((size_t)(N + 1) * 4);
    int*   csr_src = (int*)  take((size_t)E * 4);
    int*   bsum    = (int*)  take(256 * 4);
    int*   boff    = (int*)  take(256 * 4);
    float* norm    = (float*)take((size_t)N * 4);
    float* el      = (float*)take((size_t)N * H * 4);
    float* er      = (float*)take((size_t)N * H * 4);
    float* res     = (float*)take((size_t)N * HD * 4);
    float* featP   = (float*)take((size_t)N * HD * 4);
    float* hbuf    = (float*)take((size_t)N * HD * 4);
    unsigned short* fhi = (unsigned short*)take((size_t)N * INP * 2);
    unsigned short* flo = (unsigned short*)take((size_t)N * INP * 2);
    unsigned short* wrh = (unsigned short*)take((size_t)160 * INP * 2);
    unsigned short* wrl = (unsigned short*)take((size_t)160 * INP * 2);
    unsigned short* w0h = (unsigned short*)take((size_t)160 * INP * 2);
    unsigned short* w0l = (unsigned short*)take((size_t)160 * INP * 2);
    unsigned short* w1h = (unsigned short*)take((size_t)160 * HD * 2);
    unsigned short* w1l = (unsigned short*)take((size_t)160 * HD * 2);
    unsigned short* w2h = (unsigned short*)take((size_t)160 * HD * 2);
    unsigned short* w2l = (unsigned short*)take((size_t)160 * HD * 2);
    float* out = (float*)d_out;

    unsigned short* hAhi = fhi;
    unsigned short* hAlo = fhi + (size_t)N * HD;
    unsigned short* hBhi = flo;
    unsigned short* hBlo = flo + (size_t)N * HD;

    auto cdiv = [](long long a, long long b) { return (int)((a + b - 1) / b); };
    const int nb = cdiv(N, 256);

    // 1. CSR build + norm (hierarchical scan)
    hipMemsetAsync(deg, 0, (size_t)N * 4, stream);
    hipMemsetAsync(cnt, 0, (size_t)N * 4, stream);
    k_degi<<<cdiv(E, 256), 256, 0, stream>>>(dst, deg, E);
    k_scan1<<<nb, 256, 0, stream>>>(deg, rowptr, bsum, norm, N);
    k_scan2<<<1, 256, 0, stream>>>(bsum, boff, rowptr + N, nb);
    k_scan3<<<nb, 256, 0, stream>>>(rowptr, boff, N);
    k_fill<<<cdiv(E, 256), 256, 0, stream>>>(src, dst, rowptr, cnt, csr_src, E);

    // 2. weight transposes + splits, feature split
    k_splitWT<<<cdiv(160 * INP, 256), 256, 0, stream>>>(Wraw, wrh, wrl, IN, INP);
    k_splitWT<<<cdiv(160 * INP, 256), 256, 0, stream>>>(W0, w0h, w0l, IN, INP);
    k_splitWT<<<cdiv(160 * HD, 256), 256, 0, stream>>>(W1, w1h, w1l, HD, HD);
    k_splitWT<<<cdiv(160 * HD, 256), 256, 0, stream>>>(W2, w2h, w2l, HD, HD);
    k_splitX<<<cdiv((long long)N * INP, 256), 256, 0, stream>>>(features, fhi, flo, N, IN, INP);

    // 3. rawn = (features @ Wraw + braw) * norm
    k_gemm_mfma<10><<<cdiv(N, 64), 256, 0, stream>>>(fhi, flo, wrh, wrl, braw, norm, featP, N,
                                                     nullptr, nullptr, nullptr, nullptr);

    // 4. res = norm * gather_sum(rawn[src])
    k_res_gather4<<<cdiv((long long)N * 40, 256), 256, 0, stream>>>(rowptr, csr_src, featP, norm, res, N);

    // 5. layer 0 (K=300 padded 320), elr fused into GEMM
    k_gemm_mfma<10><<<cdiv(N, 64), 256, 0, stream>>>(fhi, flo, w0h, w0l, nullptr, nullptr, featP, N,
                                                     al0, ar0, el, er);
    k_gat_fused<5, 32><<<N, 64, 0, stream>>>(rowptr, csr_src, el, er, featP, nullptr,
                                             hbuf, hAhi, hAlo, 1);

    // 6. layer 1 (K=160)
    k_gemm_mfma<5><<<cdiv(N, 64), 256, 0, stream>>>(hAhi, hAlo, w1h, w1l, nullptr, nullptr, featP, N,
                                                    al1, ar1, el, er);
    k_gat_fused<5, 32><<<N, 64, 0, stream>>>(rowptr, csr_src, el, er, featP, res,
                                             hbuf, hBhi, hBlo, 2);

    // 7. layer 2 (K=160)
    k_gemm_mfma<5><<<cdiv(N, 64), 256, 0, stream>>>(hBhi, hBlo, w2h, w2l, nullptr, nullptr, featP, N,
                                                    al2, ar2, el, er);
    k_gat_fused<5, 32><<<N, 64, 0, stream>>>(rowptr, csr_src, el, er, featP, res,
                                             hbuf, nullptr, nullptr, 2);

    // 8. output GAT (H=1, D=OUT)
    k_gemv10<<<cdiv(N, 256), 256, 0, stream>>>(hbuf, Wout, featP, N, HD);
    k_elr_gen<<<cdiv(N, 256), 256, 0, stream>>>(featP, alout, arout, el, er, N, 1, OUT);
    k_gat_fused<1, 10><<<N, 64, 0, stream>>>(rowptr, csr_src, el, er, featP, nullptr,
                                             out, nullptr, nullptr, 0);
}

// Round 12
// 779.240 us; speedup vs baseline: 1.7375x; 1.2309x over previous
//
#include <hip/hip_runtime.h>
#include <hip/hip_bf16.h>

#define NEGS 0.2f

typedef __attribute__((ext_vector_type(8))) short bf16x8;
typedef __attribute__((ext_vector_type(4))) float f32x4;
typedef __attribute__((ext_vector_type(16))) float f32x16;

__device__ inline unsigned short bf16_rne(float x) {
    unsigned u = __float_as_uint(x);
    unsigned r = u + 0x7FFFu + ((u >> 16) & 1u);
    return (unsigned short)(r >> 16);
}

// ---------------- CSR build ----------------
__global__ void k_degi(const int* __restrict__ dst, int* __restrict__ deg, int E) {
    int e = blockIdx.x * blockDim.x + threadIdx.x;
    if (e < E) atomicAdd(&deg[dst[e]], 1);
}

__global__ __launch_bounds__(256)
void k_scan1(const int* __restrict__ deg, int* __restrict__ rowptr,
             int* __restrict__ bsum, float* __restrict__ norm, int N) {
    __shared__ int sdata[256];
    int t = threadIdx.x, i = blockIdx.x * 256 + t;
    int d = (i < N) ? deg[i] : 0;
    sdata[t] = d;
    __syncthreads();
    for (int off = 1; off < 256; off <<= 1) {
        int v = (t >= off) ? sdata[t - off] : 0;
        __syncthreads();
        sdata[t] += v;
        __syncthreads();
    }
    if (i < N) {
        rowptr[i] = sdata[t] - d;
        norm[i] = rsqrtf(fmaxf((float)d, 1.0f));
    }
    if (t == 255) bsum[blockIdx.x] = sdata[255];
}

__global__ __launch_bounds__(256)
void k_scan2(const int* __restrict__ bsum, int* __restrict__ boff,
             int* __restrict__ rowptrN, int nb) {
    __shared__ int sdata[256];
    int t = threadIdx.x;
    int v = (t < nb) ? bsum[t] : 0;
    sdata[t] = v;
    __syncthreads();
    for (int off = 1; off < 256; off <<= 1) {
        int x = (t >= off) ? sdata[t - off] : 0;
        __syncthreads();
        sdata[t] += x;
        __syncthreads();
    }
    if (t < nb) boff[t] = sdata[t] - v;
    if (t == 255) *rowptrN = sdata[255];
}

__global__ __launch_bounds__(256)
void k_scan3(int* __restrict__ rowptr, const int* __restrict__ boff, int N) {
    int i = blockIdx.x * 256 + threadIdx.x;
    if (i < N) rowptr[i] += boff[blockIdx.x];
}

__global__ void k_fill(const int* __restrict__ src, const int* __restrict__ dst,
                       const int* __restrict__ rowptr, int* __restrict__ cnt,
                       int* __restrict__ csr_src, int E) {
    int e = blockIdx.x * blockDim.x + threadIdx.x;
    if (e >= E) return;
    int d = dst[e];
    int pos = rowptr[d] + atomicAdd(&cnt[d], 1);
    csr_src[pos] = src[e];
}

// ---------------- bf16 hi/lo split ----------------
__global__ void k_splitX(const float* __restrict__ X, unsigned short* __restrict__ hi,
                         unsigned short* __restrict__ lo, int Nr, int K, int KP) {
    int i = blockIdx.x * blockDim.x + threadIdx.x;
    if (i >= Nr * KP) return;
    int n = i / KP, k = i - n * KP;
    float x = (k < K) ? X[(size_t)n * K + k] : 0.0f;
    unsigned short h = bf16_rne(x);
    float hf = __uint_as_float((unsigned)h << 16);
    hi[i] = h;
    lo[i] = bf16_rne(x - hf);
}

__global__ void k_splitWT(const float* __restrict__ W, unsigned short* __restrict__ hi,
                          unsigned short* __restrict__ lo, int K, int KP) {
    int i = blockIdx.x * blockDim.x + threadIdx.x;
    if (i >= 160 * KP) return;
    int c = i / KP, k = i - c * KP;
    float x = (k < K) ? W[(size_t)k * 160 + c] : 0.0f;
    unsigned short h = bf16_rne(x);
    float hf = __uint_as_float((unsigned)h << 16);
    hi[i] = h;
    lo[i] = bf16_rne(x - hf);
}

// ---------------- MFMA GEMM v2: 32x32x16, LDS-staged B, double-buffered ---
// Block: 256 thr = 4 waves; wave owns 32 rows x 160 cols (5 acc tiles).
// B (WT hi/lo) staged per 32-k tile into LDS (pad stride 40), shared by waves.
// A prefetched to regs. One barrier per k-tile. bf16x3 precision scheme.
template<int KP>   // 160 or 320
__global__ __launch_bounds__(256)
void k_gemm_mfma32(const unsigned short* __restrict__ Xhi, const unsigned short* __restrict__ Xlo,
                   const unsigned short* __restrict__ WThi, const unsigned short* __restrict__ WTlo,
                   const float* __restrict__ bias, const float* __restrict__ rowscale,
                   float* __restrict__ C, int Nrows) {
    constexpr int NKT = KP / 32;
    __shared__ __align__(16) unsigned short Bs[2][2][160][40];  // [buf][hi/lo][col][k+pad] 51.2KB
    const int tid = threadIdx.x;
    const int lane = tid & 63;
    const int wave = tid >> 6;
    const int lc = lane & 31;      // A-row / B-col within tile
    const int lh = lane >> 5;      // k-half selector
    const int row0 = blockIdx.x * 128 + wave * 32;

    int arow = row0 + lc;
    int arc = (arow < Nrows) ? arow : (Nrows - 1);
    const unsigned short* pAh = Xhi + (size_t)arc * KP + lh * 8;
    const unsigned short* pAl = Xlo + (size_t)arc * KP + lh * 8;

    bf16x8 breg[5];
    auto loadB = [&](int kt) {             // global -> regs (1280 b128 chunks / 256 thr)
        #pragma unroll
        for (int j = 0; j < 5; ++j) {
            int idx = tid + j * 256;
            const unsigned short* sp = (idx < 640) ? WThi : WTlo;
            int i = (idx < 640) ? idx : idx - 640;
            int col = i >> 2, ko = (i & 3) * 8;
            breg[j] = *(const bf16x8*)(sp + (size_t)col * KP + kt * 32 + ko);
        }
    };
    auto storeB = [&](int buf) {           // regs -> LDS
        #pragma unroll
        for (int j = 0; j < 5; ++j) {
            int idx = tid + j * 256;
            int hl = (idx < 640) ? 0 : 1;
            int i = idx - hl * 640;
            int col = i >> 2, ko = (i & 3) * 8;
            *(bf16x8*)(&Bs[buf][hl][col][ko]) = breg[j];
        }
    };
    bf16x8 Ah[2], Al[2];
    auto loadA = [&](int kt, bf16x8* ah, bf16x8* al) {
        #pragma unroll
        for (int k16 = 0; k16 < 2; ++k16) {
            ah[k16] = *(const bf16x8*)(pAh + kt * 32 + k16 * 16);
            al[k16] = *(const bf16x8*)(pAl + kt * 32 + k16 * 16);
        }
    };

    f32x16 acc[5] = {};
    loadB(0); loadA(0, Ah, Al);
    storeB(0);
    __syncthreads();
    for (int kt = 0; kt < NKT; ++kt) {
        int cur = kt & 1;
        bf16x8 Ah2[2], Al2[2];
        if (kt + 1 < NKT) { loadB(kt + 1); loadA(kt + 1, Ah2, Al2); }
        #pragma unroll
        for (int k16 = 0; k16 < 2; ++k16) {
            #pragma unroll
            for (int ct = 0; ct < 5; ++ct) {
                bf16x8 bh = *(const bf16x8*)(&Bs[cur][0][ct * 32 + lc][k16 * 16 + lh * 8]);
                bf16x8 bl = *(const bf16x8*)(&Bs[cur][1][ct * 32 + lc][k16 * 16 + lh * 8]);
                acc[ct] = __builtin_amdgcn_mfma_f32_32x32x16_bf16(Ah[k16], bh, acc[ct], 0, 0, 0);
                acc[ct] = __builtin_amdgcn_mfma_f32_32x32x16_bf16(Ah[k16], bl, acc[ct], 0, 0, 0);
                acc[ct] = __builtin_amdgcn_mfma_f32_32x32x16_bf16(Al[k16], bh, acc[ct], 0, 0, 0);
            }
        }
        if (kt + 1 < NKT) {
            storeB(cur ^ 1);
            Ah[0] = Ah2[0]; Ah[1] = Ah2[1]; Al[0] = Al2[0]; Al[1] = Al2[1];
        }
        __syncthreads();
    }

    // epilogue: C/D layout col = lane&31 (+ct*32), row = (r&3)+8*(r>>2)+4*lh
    #pragma unroll
    for (int r = 0; r < 16; ++r) {
        int row = row0 + (r & 3) + 8 * (r >> 2) + 4 * lh;
        if (row >= Nrows) continue;
        float sc = rowscale ? rowscale[row] : 1.0f;
        #pragma unroll
        for (int ct = 0; ct < 5; ++ct) {
            int col = ct * 32 + lc;
            float v = acc[ct][r];
            if (bias) v += bias[col];
            C[(size_t)row * 160 + col] = v * sc;
        }
    }
}

// ---------------- small GEMM for Wout ----------------
__global__ __launch_bounds__(256)
void k_gemv10(const float* __restrict__ A, const float* __restrict__ B,
              float* __restrict__ C, int Nrows, int K) {
    __shared__ float Bs[160 * 10];
    for (int i = threadIdx.x; i < K * 10; i += 256) Bs[i] = B[i];
    __syncthreads();
    int row = blockIdx.x * 256 + threadIdx.x;
    if (row >= Nrows) return;
    float acc[10] = {};
    const float4* a = reinterpret_cast<const float4*>(A + (size_t)row * K);
    for (int kq = 0; kq < K / 4; ++kq) {
        float4 v = a[kq];
        int k = kq * 4;
        #pragma unroll
        for (int j = 0; j < 10; ++j)
            acc[j] += v.x * Bs[(k + 0) * 10 + j] + v.y * Bs[(k + 1) * 10 + j]
                    + v.z * Bs[(k + 2) * 10 + j] + v.w * Bs[(k + 3) * 10 + j];
    }
    #pragma unroll
    for (int j = 0; j < 10; ++j) C[(size_t)row * 10 + j] = acc[j];
}

// ---------------- attention logits el/er ----------------
__global__ void k_elr32(const float* __restrict__ feat, const float* __restrict__ al,
                        const float* __restrict__ ar, float* __restrict__ el,
                        float* __restrict__ er, int N, int H) {
    int i = blockIdx.x * blockDim.x + threadIdx.x;
    if (i >= N * H) return;
    int h = i % H;
    const float4* f = (const float4*)(feat + (size_t)i * 32);
    const float4* a = (const float4*)(al + h * 32);
    const float4* b = (const float4*)(ar + h * 32);
    float sl = 0.0f, sr = 0.0f;
    #pragma unroll
    for (int d = 0; d < 8; d++) {
        float4 v = f[d], x = a[d], y = b[d];
        sl += v.x * x.x + v.y * x.y + v.z * x.z + v.w * x.w;
        sr += v.x * y.x + v.y * y.y + v.z * y.z + v.w * y.w;
    }
    el[i] = sl; er[i] = sr;
}

__global__ void k_elr_gen(const float* __restrict__ feat, const float* __restrict__ al,
                          const float* __restrict__ ar, float* __restrict__ el,
                          float* __restrict__ er, int N, int H, int D) {
    int i = blockIdx.x * blockDim.x + threadIdx.x;
    if (i >= N * H) return;
    int h = i % H;
    const float* f = feat + (size_t)i * D;
    const float* a = al + h * D;
    const float* b = ar + h * D;
    float sl = 0.0f, sr = 0.0f;
    for (int d = 0; d < D; d++) { float v = f[d]; sl += v * a[d]; sr += v * b[d]; }
    el[i] = sl; er[i] = sr;
}

// ---------------- fused GAT: online softmax + float4 weighted gather ----
template<int H, int D>
__global__ __launch_bounds__(64)
void k_gat_fused(const int* __restrict__ rowptr, const int* __restrict__ csr_src,
                 const float* __restrict__ el, const float* __restrict__ er,
                 const float* __restrict__ feat, const float* __restrict__ res,
                 float* __restrict__ out, unsigned short* __restrict__ ohi,
                 unsigned short* __restrict__ olo, int relu_mode) {
    constexpr int HD = H * D;
    const int n = blockIdx.x;
    const int lane = threadIdx.x;
    const int beg = rowptr[n], end = rowptr[n + 1];

    float erh[H];
    #pragma unroll
    for (int h = 0; h < H; ++h) erh[h] = er[n * H + h];

    float m[H], ssum[H];
    #pragma unroll
    for (int h = 0; h < H; ++h) { m[h] = -1e30f; ssum[h] = 0.0f; }
    for (int j = beg + lane; j < end; j += 64) {
        int s = csr_src[j];
        #pragma unroll
        for (int h = 0; h < H; ++h) {
            float x = el[s * H + h] + erh[h];
            x = (x > 0.0f) ? x : (NEGS * x);
            float mn = fmaxf(m[h], x);
            ssum[h] = ssum[h] * __expf(m[h] - mn) + __expf(x - mn);
            m[h] = mn;
        }
    }
    float inv[H];
    #pragma unroll
    for (int h = 0; h < H; ++h) {
        #pragma unroll
        for (int off = 32; off; off >>= 1) {
            float mo = __shfl_xor(m[h], off, 64);
            float so = __shfl_xor(ssum[h], off, 64);
            float mn = fmaxf(m[h], mo);
            ssum[h] = ssum[h] * __expf(m[h] - mn) + so * __expf(mo - mn);
            m[h] = mn;
        }
        inv[h] = (ssum[h] > 0.0f) ? 1.0f / ssum[h] : 0.0f;
    }

    __shared__ float s_alpha[64 * H];
    __shared__ int   s_src[64];

    if constexpr ((D & 3) == 0) {
        constexpr int NV = HD / 4;
        const int hc = (lane * 4) / D;
        float4 acc = make_float4(0.f, 0.f, 0.f, 0.f);
        for (int chunk = beg; chunk < end; chunk += 64) {
            int j = chunk + lane;
            if (j < end) {
                int s = csr_src[j];
                s_src[lane] = s;
                #pragma unroll
                for (int h = 0; h < H; ++h) {
                    float x = el[s * H + h] + erh[h];
                    x = (x > 0.0f) ? x : (NEGS * x);
                    s_alpha[lane * H + h] = __expf(x - m[h]) * inv[h];
                }
            }
            __syncthreads();
            int cnt = min(64, end - chunk);
            if (lane < NV) {
                for (int t = 0; t < cnt; ++t) {
                    const float4 v = *reinterpret_cast<const float4*>(
                        feat + (size_t)s_src[t] * HD + lane * 4);
                    float a = s_alpha[t * H + hc];
                    acc.x += a * v.x; acc.y += a * v.y;
                    acc.z += a * v.z; acc.w += a * v.w;
                }
            }
            __syncthreads();
        }
        if (lane < NV) {
            float4 v = acc;
            if (relu_mode == 2) {
                const float4 rv = *reinterpret_cast<const float4*>(
                    res + (size_t)n * HD + lane * 4);
                v.x += rv.x; v.y += rv.y; v.z += rv.z; v.w += rv.w;
            }
            if (relu_mode) {
                v.x = fmaxf(v.x, 0.f); v.y = fmaxf(v.y, 0.f);
                v.z = fmaxf(v.z, 0.f); v.w = fmaxf(v.w, 0.f);
            }
            *reinterpret_cast<float4*>(out + (size_t)n * HD + lane * 4) = v;
            if (ohi) {
                ushort4 hv, lv;
                float c[4] = {v.x, v.y, v.z, v.w};
                unsigned short hh[4], ll[4];
                #pragma unroll
                for (int e2 = 0; e2 < 4; ++e2) {
                    hh[e2] = bf16_rne(c[e2]);
                    float hf = __uint_as_float((unsigned)hh[e2] << 16);
                    ll[e2] = bf16_rne(c[e2] - hf);
                }
                hv.x = hh[0]; hv.y = hh[1]; hv.z = hh[2]; hv.w = hh[3];
                lv.x = ll[0]; lv.y = ll[1]; lv.z = ll[2]; lv.w = ll[3];
                *reinterpret_cast<ushort4*>(ohi + (size_t)n * HD + lane * 4) = hv;
                *reinterpret_cast<ushort4*>(olo + (size_t)n * HD + lane * 4) = lv;
            }
        }
    } else {
        constexpr int SLOTS = (HD + 63) / 64;
        float acc[SLOTS];
        #pragma unroll
        for (int r = 0; r < SLOTS; ++r) acc[r] = 0.0f;
        for (int chunk = beg; chunk < end; chunk += 64) {
            int j = chunk + lane;
            if (j < end) {
                int s = csr_src[j];
                s_src[lane] = s;
                #pragma unroll
                for (int h = 0; h < H; ++h) {
                    float x = el[s * H + h] + erh[h];
                    x = (x > 0.0f) ? x : (NEGS * x);
                    s_alpha[lane * H + h] = __expf(x - m[h]) * inv[h];
                }
            }
            __syncthreads();
            int cnt = min(64, end - chunk);
            for (int t = 0; t < cnt; ++t) {
                const float* fr = feat + (size_t)s_src[t] * HD;
                #pragma unroll
                for (int r = 0; r < SLOTS; ++r) {
                    int hd = r * 64 + lane;
                    if (hd < HD)
                        acc[r] += s_alpha[t * H + hd / D] * fr[hd];
                }
            }
            __syncthreads();
        }
        #pragma unroll
        for (int r = 0; r < SLOTS; ++r) {
            int hd = r * 64 + lane;
            if (hd < HD) {
                float v = acc[r];
                if (relu_mode == 2) v += res[(size_t)n * HD + hd];
                if (relu_mode) v = fmaxf(v, 0.0f);
                out[(size_t)n * HD + hd] = v;
            }
        }
    }
}

// ---------------- residual: res = norm_dst * sum_in(rawn[src]), float4 ----
__global__ void k_res_gather4(const int* __restrict__ rowptr, const int* __restrict__ csr_src,
                              const float* __restrict__ rawn, const float* __restrict__ norm,
                              float* __restrict__ res, int N) {
    constexpr int M4 = 40;
    int i = blockIdx.x * blockDim.x + threadIdx.x;
    if (i >= N * M4) return;
    int n = i / M4, q = i - n * M4;
    int beg = rowptr[n], end = rowptr[n + 1];
    float4 acc = make_float4(0.f, 0.f, 0.f, 0.f);
    for (int j = beg; j < end; ++j) {
        const float4 v = *reinterpret_cast<const float4*>(
            rawn + (size_t)csr_src[j] * 160 + q * 4);
        acc.x += v.x; acc.y += v.y; acc.z += v.z; acc.w += v.w;
    }
    float sc = norm[n];
    acc.x *= sc; acc.y *= sc; acc.z *= sc; acc.w *= sc;
    *reinterpret_cast<float4*>(res + (size_t)n * 160 + q * 4) = acc;
}

// ---------------- launch ----------------
extern "C" void kernel_launch(void* const* d_in, const int* in_sizes, int n_in,
                              void* d_out, int out_size, void* d_ws, size_t ws_size,
                              hipStream_t stream) {
    const float* features = (const float*)d_in[0];
    const int*   src      = (const int*)d_in[1];
    const int*   dst      = (const int*)d_in[2];
    const float* W0   = (const float*)d_in[3];
    const float* al0  = (const float*)d_in[4];
    const float* ar0  = (const float*)d_in[5];
    const float* W1   = (const float*)d_in[6];
    const float* al1  = (const float*)d_in[7];
    const float* ar1  = (const float*)d_in[8];
    const float* W2   = (const float*)d_in[9];
    const float* al2  = (const float*)d_in[10];
    const float* ar2  = (const float*)d_in[11];
    const float* Wout = (const float*)d_in[12];
    const float* alout= (const float*)d_in[13];
    const float* arout= (const float*)d_in[14];
    const float* Wraw = (const float*)d_in[15];
    const float* braw = (const float*)d_in[16];

    const int IN = 300, INP = 320, H = 5, D = 32, HD = 160, OUT = 10;
    const int N = in_sizes[0] / IN;   // 50000
    const int E = in_sizes[1];        // 800000

    char* w = (char*)d_ws;
    auto take = [&](size_t bytes) { char* r = w; w += (bytes + 255) & ~size_t(255); return r; };
    int*   deg     = (int*)  take((size_t)N * 4);
    int*   cnt     = (int*)  take((size_t)N * 4);
    int*   rowptr  = (int*)  take((size_t)(N + 1) * 4);
    int*   csr_src = (int*)  take((size_t)E * 4);
    int*   bsum    = (int*)  take(256 * 4);
    int*   boff    = (int*)  take(256 * 4);
    float* norm    = (float*)take((size_t)N * 4);
    float* el      = (float*)take((size_t)N * H * 4);
    float* er      = (float*)take((size_t)N * H * 4);
    float* res     = (float*)take((size_t)N * HD * 4);
    float* featP   = (float*)take((size_t)N * HD * 4);
    float* hbuf    = (float*)take((size_t)N * HD * 4);
    unsigned short* fhi = (unsigned short*)take((size_t)N * INP * 2);
    unsigned short* flo = (unsigned short*)take((size_t)N * INP * 2);
    unsigned short* wrh = (unsigned short*)take((size_t)160 * INP * 2);
    unsigned short* wrl = (unsigned short*)take((size_t)160 * INP * 2);
    unsigned short* w0h = (unsigned short*)take((size_t)160 * INP * 2);
    unsigned short* w0l = (unsigned short*)take((size_t)160 * INP * 2);
    unsigned short* w1h = (unsigned short*)take((size_t)160 * HD * 2);
    unsigned short* w1l = (unsigned short*)take((size_t)160 * HD * 2);
    unsigned short* w2h = (unsigned short*)take((size_t)160 * HD * 2);
    unsigned short* w2l = (unsigned short*)take((size_t)160 * HD * 2);
    float* out = (float*)d_out;

    unsigned short* hAhi = fhi;
    unsigned short* hAlo = fhi + (size_t)N * HD;
    unsigned short* hBhi = flo;
    unsigned short* hBlo = flo + (size_t)N * HD;

    auto cdiv = [](long long a, long long b) { return (int)((a + b - 1) / b); };
    const int nb = cdiv(N, 256);

    // 1. CSR build + norm (hierarchical scan)
    hipMemsetAsync(deg, 0, (size_t)N * 4, stream);
    hipMemsetAsync(cnt, 0, (size_t)N * 4, stream);
    k_degi<<<cdiv(E, 256), 256, 0, stream>>>(dst, deg, E);
    k_scan1<<<nb, 256, 0, stream>>>(deg, rowptr, bsum, norm, N);
    k_scan2<<<1, 256, 0, stream>>>(bsum, boff, rowptr + N, nb);
    k_scan3<<<nb, 256, 0, stream>>>(rowptr, boff, N);
    k_fill<<<cdiv(E, 256), 256, 0, stream>>>(src, dst, rowptr, cnt, csr_src, E);

    // 2. weight transposes + splits, feature split
    k_splitWT<<<cdiv(160 * INP, 256), 256, 0, stream>>>(Wraw, wrh, wrl, IN, INP);
    k_splitWT<<<cdiv(160 * INP, 256), 256, 0, stream>>>(W0, w0h, w0l, IN, INP);
    k_splitWT<<<cdiv(160 * HD, 256), 256, 0, stream>>>(W1, w1h, w1l, HD, HD);
    k_splitWT<<<cdiv(160 * HD, 256), 256, 0, stream>>>(W2, w2h, w2l, HD, HD);
    k_splitX<<<cdiv((long long)N * INP, 256), 256, 0, stream>>>(features, fhi, flo, N, IN, INP);

    // 3. rawn = (features @ Wraw + braw) * norm
    k_gemm_mfma32<320><<<cdiv(N, 128), 256, 0, stream>>>(fhi, flo, wrh, wrl, braw, norm, featP, N);

    // 4. res = norm * gather_sum(rawn[src])
    k_res_gather4<<<cdiv((long long)N * 40, 256), 256, 0, stream>>>(rowptr, csr_src, featP, norm, res, N);

    // 5. layer 0 (K=300 padded 320)
    k_gemm_mfma32<320><<<cdiv(N, 128), 256, 0, stream>>>(fhi, flo, w0h, w0l, nullptr, nullptr, featP, N);
    k_elr32<<<cdiv((long long)N * H, 256), 256, 0, stream>>>(featP, al0, ar0, el, er, N, H);
    k_gat_fused<5, 32><<<N, 64, 0, stream>>>(rowptr, csr_src, el, er, featP, nullptr,
                                             hbuf, hAhi, hAlo, 1);

    // 6. layer 1 (K=160)
    k_gemm_mfma32<160><<<cdiv(N, 128), 256, 0, stream>>>(hAhi, hAlo, w1h, w1l, nullptr, nullptr, featP, N);
    k_elr32<<<cdiv((long long)N * H, 256), 256, 0, stream>>>(featP, al1, ar1, el, er, N, H);
    k_gat_fused<5, 32><<<N, 64, 0, stream>>>(rowptr, csr_src, el, er, featP, res,
                                             hbuf, hBhi, hBlo, 2);

    // 7. layer 2 (K=160)
    k_gemm_mfma32<160><<<cdiv(N, 128), 256, 0, stream>>>(hBhi, hBlo, w2h, w2l, nullptr, nullptr, featP, N);
    k_elr32<<<cdiv((long long)N * H, 256), 256, 0, stream>>>(featP, al2, ar2, el, er, N, H);
    k_gat_fused<5, 32><<<N, 64, 0, stream>>>(rowptr, csr_src, el, er, featP, res,
                                             hbuf, nullptr, nullptr, 2);

    // 8. output GAT (H=1, D=OUT)
    k_gemv10<<<cdiv(N, 256), 256, 0, stream>>>(hbuf, Wout, featP, N, HD);
    k_elr_gen<<<cdiv(N, 256), 256, 0, stream>>>(featP, alout, arout, el, er, N, 1, OUT);
    k_gat_fused<1, 10><<<N, 64, 0, stream>>>(rowptr, csr_src, el, er, featP, nullptr,
                                             out, nullptr, nullptr, 0);
}

// Round 13
// 778.682 us; speedup vs baseline: 1.7387x; 1.0007x over previous
//
#include <hip/hip_runtime.h>
#include <hip/hip_bf16.h>

#define NEGS 0.2f

typedef __attribute__((ext_vector_type(8))) short bf16x8;
typedef __attribute__((ext_vector_type(4))) float f32x4;
typedef __attribute__((ext_vector_type(16))) float f32x16;

__device__ inline unsigned short bf16_rne(float x) {
    unsigned u = __float_as_uint(x);
    unsigned r = u + 0x7FFFu + ((u >> 16) & 1u);
    return (unsigned short)(r >> 16);
}

// ---------------- CSR build ----------------
__global__ void k_degi(const int* __restrict__ dst, int* __restrict__ deg, int E) {
    int e = blockIdx.x * blockDim.x + threadIdx.x;
    if (e < E) atomicAdd(&deg[dst[e]], 1);
}

__global__ __launch_bounds__(256)
void k_scan1(const int* __restrict__ deg, int* __restrict__ rowptr,
             int* __restrict__ bsum, float* __restrict__ norm, int N) {
    __shared__ int sdata[256];
    int t = threadIdx.x, i = blockIdx.x * 256 + t;
    int d = (i < N) ? deg[i] : 0;
    sdata[t] = d;
    __syncthreads();
    for (int off = 1; off < 256; off <<= 1) {
        int v = (t >= off) ? sdata[t - off] : 0;
        __syncthreads();
        sdata[t] += v;
        __syncthreads();
    }
    if (i < N) {
        rowptr[i] = sdata[t] - d;
        norm[i] = rsqrtf(fmaxf((float)d, 1.0f));
    }
    if (t == 255) bsum[blockIdx.x] = sdata[255];
}

__global__ __launch_bounds__(256)
void k_scan2(const int* __restrict__ bsum, int* __restrict__ boff,
             int* __restrict__ rowptrN, int nb) {
    __shared__ int sdata[256];
    int t = threadIdx.x;
    int v = (t < nb) ? bsum[t] : 0;
    sdata[t] = v;
    __syncthreads();
    for (int off = 1; off < 256; off <<= 1) {
        int x = (t >= off) ? sdata[t - off] : 0;
        __syncthreads();
        sdata[t] += x;
        __syncthreads();
    }
    if (t < nb) boff[t] = sdata[t] - v;
    if (t == 255) *rowptrN = sdata[255];
}

__global__ __launch_bounds__(256)
void k_scan3(int* __restrict__ rowptr, const int* __restrict__ boff, int N) {
    int i = blockIdx.x * 256 + threadIdx.x;
    if (i < N) rowptr[i] += boff[blockIdx.x];
}

__global__ void k_fill(const int* __restrict__ src, const int* __restrict__ dst,
                       const int* __restrict__ rowptr, int* __restrict__ cnt,
                       int* __restrict__ csr_src, int E) {
    int e = blockIdx.x * blockDim.x + threadIdx.x;
    if (e >= E) return;
    int d = dst[e];
    int pos = rowptr[d] + atomicAdd(&cnt[d], 1);
    csr_src[pos] = src[e];
}

// ---------------- bf16 hi/lo split ----------------
__global__ void k_splitX(const float* __restrict__ X, unsigned short* __restrict__ hi,
                         unsigned short* __restrict__ lo, int Nr, int K, int KP) {
    int i = blockIdx.x * blockDim.x + threadIdx.x;
    if (i >= Nr * KP) return;
    int n = i / KP, k = i - n * KP;
    float x = (k < K) ? X[(size_t)n * K + k] : 0.0f;
    unsigned short h = bf16_rne(x);
    float hf = __uint_as_float((unsigned)h << 16);
    hi[i] = h;
    lo[i] = bf16_rne(x - hf);
}

__global__ void k_splitWT(const float* __restrict__ W, unsigned short* __restrict__ hi,
                          unsigned short* __restrict__ lo, int K, int KP) {
    int i = blockIdx.x * blockDim.x + threadIdx.x;
    if (i >= 160 * KP) return;
    int c = i / KP, k = i - c * KP;
    float x = (k < K) ? W[(size_t)k * 160 + c] : 0.0f;
    unsigned short h = bf16_rne(x);
    float hf = __uint_as_float((unsigned)h << 16);
    hi[i] = h;
    lo[i] = bf16_rne(x - hf);
}

// ---------------- MFMA GEMM: 32x32x16, LDS-staged B, double-buffered ------
template<int KP>   // 160 or 320
__global__ __launch_bounds__(256)
void k_gemm_mfma32(const unsigned short* __restrict__ Xhi, const unsigned short* __restrict__ Xlo,
                   const unsigned short* __restrict__ WThi, const unsigned short* __restrict__ WTlo,
                   const float* __restrict__ bias, const float* __restrict__ rowscale,
                   float* __restrict__ C, int Nrows) {
    constexpr int NKT = KP / 32;
    __shared__ __align__(16) unsigned short Bs[2][2][160][40];
    const int tid = threadIdx.x;
    const int lane = tid & 63;
    const int wave = tid >> 6;
    const int lc = lane & 31;
    const int lh = lane >> 5;
    const int row0 = blockIdx.x * 128 + wave * 32;

    int arow = row0 + lc;
    int arc = (arow < Nrows) ? arow : (Nrows - 1);
    const unsigned short* pAh = Xhi + (size_t)arc * KP + lh * 8;
    const unsigned short* pAl = Xlo + (size_t)arc * KP + lh * 8;

    bf16x8 breg[5];
    auto loadB = [&](int kt) {
        #pragma unroll
        for (int j = 0; j < 5; ++j) {
            int idx = tid + j * 256;
            const unsigned short* sp = (idx < 640) ? WThi : WTlo;
            int i = (idx < 640) ? idx : idx - 640;
            int col = i >> 2, ko = (i & 3) * 8;
            breg[j] = *(const bf16x8*)(sp + (size_t)col * KP + kt * 32 + ko);
        }
    };
    auto storeB = [&](int buf) {
        #pragma unroll
        for (int j = 0; j < 5; ++j) {
            int idx = tid + j * 256;
            int hl = (idx < 640) ? 0 : 1;
            int i = idx - hl * 640;
            int col = i >> 2, ko = (i & 3) * 8;
            *(bf16x8*)(&Bs[buf][hl][col][ko]) = breg[j];
        }
    };
    bf16x8 Ah[2], Al[2];
    auto loadA = [&](int kt, bf16x8* ah, bf16x8* al) {
        #pragma unroll
        for (int k16 = 0; k16 < 2; ++k16) {
            ah[k16] = *(const bf16x8*)(pAh + kt * 32 + k16 * 16);
            al[k16] = *(const bf16x8*)(pAl + kt * 32 + k16 * 16);
        }
    };

    f32x16 acc[5] = {};
    loadB(0); loadA(0, Ah, Al);
    storeB(0);
    __syncthreads();
    for (int kt = 0; kt < NKT; ++kt) {
        int cur = kt & 1;
        bf16x8 Ah2[2], Al2[2];
        if (kt + 1 < NKT) { loadB(kt + 1); loadA(kt + 1, Ah2, Al2); }
        #pragma unroll
        for (int k16 = 0; k16 < 2; ++k16) {
            #pragma unroll
            for (int ct = 0; ct < 5; ++ct) {
                bf16x8 bh = *(const bf16x8*)(&Bs[cur][0][ct * 32 + lc][k16 * 16 + lh * 8]);
                bf16x8 bl = *(const bf16x8*)(&Bs[cur][1][ct * 32 + lc][k16 * 16 + lh * 8]);
                acc[ct] = __builtin_amdgcn_mfma_f32_32x32x16_bf16(Ah[k16], bh, acc[ct], 0, 0, 0);
                acc[ct] = __builtin_amdgcn_mfma_f32_32x32x16_bf16(Ah[k16], bl, acc[ct], 0, 0, 0);
                acc[ct] = __builtin_amdgcn_mfma_f32_32x32x16_bf16(Al[k16], bh, acc[ct], 0, 0, 0);
            }
        }
        if (kt + 1 < NKT) {
            storeB(cur ^ 1);
            Ah[0] = Ah2[0]; Ah[1] = Ah2[1]; Al[0] = Al2[0]; Al[1] = Al2[1];
        }
        __syncthreads();
    }

    #pragma unroll
    for (int r = 0; r < 16; ++r) {
        int row = row0 + (r & 3) + 8 * (r >> 2) + 4 * lh;
        if (row >= Nrows) continue;
        float sc = rowscale ? rowscale[row] : 1.0f;
        #pragma unroll
        for (int ct = 0; ct < 5; ++ct) {
            int col = ct * 32 + lc;
            float v = acc[ct][r];
            if (bias) v += bias[col];
            C[(size_t)row * 160 + col] = v * sc;
        }
    }
}

// ---------------- small GEMM for Wout ----------------
__global__ __launch_bounds__(256)
void k_gemv10(const float* __restrict__ A, const float* __restrict__ B,
              float* __restrict__ C, int Nrows, int K) {
    __shared__ float Bs[160 * 10];
    for (int i = threadIdx.x; i < K * 10; i += 256) Bs[i] = B[i];
    __syncthreads();
    int row = blockIdx.x * 256 + threadIdx.x;
    if (row >= Nrows) return;
    float acc[10] = {};
    const float4* a = reinterpret_cast<const float4*>(A + (size_t)row * K);
    for (int kq = 0; kq < K / 4; ++kq) {
        float4 v = a[kq];
        int k = kq * 4;
        #pragma unroll
        for (int j = 0; j < 10; ++j)
            acc[j] += v.x * Bs[(k + 0) * 10 + j] + v.y * Bs[(k + 1) * 10 + j]
                    + v.z * Bs[(k + 2) * 10 + j] + v.w * Bs[(k + 3) * 10 + j];
    }
    #pragma unroll
    for (int j = 0; j < 10; ++j) C[(size_t)row * 10 + j] = acc[j];
}

// ---------------- attention logits el/er ----------------
__global__ void k_elr32(const float* __restrict__ feat, const float* __restrict__ al,
                        const float* __restrict__ ar, float* __restrict__ el,
                        float* __restrict__ er, int N, int H) {
    int i = blockIdx.x * blockDim.x + threadIdx.x;
    if (i >= N * H) return;
    int h = i % H;
    const float4* f = (const float4*)(feat + (size_t)i * 32);
    const float4* a = (const float4*)(al + h * 32);
    const float4* b = (const float4*)(ar + h * 32);
    float sl = 0.0f, sr = 0.0f;
    #pragma unroll
    for (int d = 0; d < 8; d++) {
        float4 v = f[d], x = a[d], y = b[d];
        sl += v.x * x.x + v.y * x.y + v.z * x.z + v.w * x.w;
        sr += v.x * y.x + v.y * y.y + v.z * y.z + v.w * y.w;
    }
    el[i] = sl; er[i] = sr;
}

__global__ void k_elr_gen(const float* __restrict__ feat, const float* __restrict__ al,
                          const float* __restrict__ ar, float* __restrict__ el,
                          float* __restrict__ er, int N, int H, int D) {
    int i = blockIdx.x * blockDim.x + threadIdx.x;
    if (i >= N * H) return;
    int h = i % H;
    const float* f = feat + (size_t)i * D;
    const float* a = al + h * D;
    const float* b = ar + h * D;
    float sl = 0.0f, sr = 0.0f;
    for (int d = 0; d < D; d++) { float v = f[d]; sl += v * a[d]; sr += v * b[d]; }
    el[i] = sl; er[i] = sr;
}

// ---------------- fused GAT v3: single-pass unnormalized softmax gather ----
// out = (sum_e w_e * feat[src_e]) / (sum_e w_e),  w_e = exp(leaky(el+er)).
// Softmax is shift-invariant; logits are O(10) here so exp cannot overflow.
// One edge pass: per-chunk alpha compute + per-lane partial wsum + gather;
// single add-butterfly at the end; normalize in the epilogue.
template<int H, int D>
__global__ __launch_bounds__(64)
void k_gat_fused(const int* __restrict__ rowptr, const int* __restrict__ csr_src,
                 const float* __restrict__ el, const float* __restrict__ er,
                 const float* __restrict__ feat, const float* __restrict__ res,
                 float* __restrict__ out, unsigned short* __restrict__ ohi,
                 unsigned short* __restrict__ olo, int relu_mode) {
    constexpr int HD = H * D;
    const int n = blockIdx.x;
    const int lane = threadIdx.x;
    const int beg = rowptr[n], end = rowptr[n + 1];

    float erh[H];
    #pragma unroll
    for (int h = 0; h < H; ++h) erh[h] = er[n * H + h];

    __shared__ float s_alpha[64 * H];
    __shared__ int   s_src[64];

    float wsum[H];
    #pragma unroll
    for (int h = 0; h < H; ++h) wsum[h] = 0.0f;

    if constexpr ((D & 3) == 0) {
        constexpr int NV = HD / 4;
        const int hc = (lane * 4) / D;
        float4 acc = make_float4(0.f, 0.f, 0.f, 0.f);
        for (int chunk = beg; chunk < end; chunk += 64) {
            int j = chunk + lane;
            if (j < end) {
                int s = csr_src[j];
                s_src[lane] = s;
                #pragma unroll
                for (int h = 0; h < H; ++h) {
                    float x = el[s * H + h] + erh[h];
                    x = (x > 0.0f) ? x : (NEGS * x);
                    float w = __expf(x);
                    s_alpha[lane * H + h] = w;
                    wsum[h] += w;
                }
            }
            __syncthreads();
            int cnt = min(64, end - chunk);
            if (lane < NV) {
                for (int t = 0; t < cnt; ++t) {
                    const float4 v = *reinterpret_cast<const float4*>(
                        feat + (size_t)s_src[t] * HD + lane * 4);
                    float a = s_alpha[t * H + hc];
                    acc.x += a * v.x; acc.y += a * v.y;
                    acc.z += a * v.z; acc.w += a * v.w;
                }
            }
            __syncthreads();
        }
        #pragma unroll
        for (int h = 0; h < H; ++h) {
            #pragma unroll
            for (int off = 32; off; off >>= 1)
                wsum[h] += __shfl_xor(wsum[h], off, 64);
        }
        if (lane < NV) {
            float inv = (wsum[hc] > 0.0f) ? 1.0f / wsum[hc] : 0.0f;
            float4 v;
            v.x = acc.x * inv; v.y = acc.y * inv;
            v.z = acc.z * inv; v.w = acc.w * inv;
            if (relu_mode == 2) {
                const float4 rv = *reinterpret_cast<const float4*>(
                    res + (size_t)n * HD + lane * 4);
                v.x += rv.x; v.y += rv.y; v.z += rv.z; v.w += rv.w;
            }
            if (relu_mode) {
                v.x = fmaxf(v.x, 0.f); v.y = fmaxf(v.y, 0.f);
                v.z = fmaxf(v.z, 0.f); v.w = fmaxf(v.w, 0.f);
            }
            *reinterpret_cast<float4*>(out + (size_t)n * HD + lane * 4) = v;
            if (ohi) {
                ushort4 hv, lv;
                float c[4] = {v.x, v.y, v.z, v.w};
                unsigned short hh[4], ll[4];
                #pragma unroll
                for (int e2 = 0; e2 < 4; ++e2) {
                    hh[e2] = bf16_rne(c[e2]);
                    float hf = __uint_as_float((unsigned)hh[e2] << 16);
                    ll[e2] = bf16_rne(c[e2] - hf);
                }
                hv.x = hh[0]; hv.y = hh[1]; hv.z = hh[2]; hv.w = hh[3];
                lv.x = ll[0]; lv.y = ll[1]; lv.z = ll[2]; lv.w = ll[3];
                *reinterpret_cast<ushort4*>(ohi + (size_t)n * HD + lane * 4) = hv;
                *reinterpret_cast<ushort4*>(olo + (size_t)n * HD + lane * 4) = lv;
            }
        }
    } else {
        constexpr int SLOTS = (HD + 63) / 64;
        float acc[SLOTS];
        #pragma unroll
        for (int r = 0; r < SLOTS; ++r) acc[r] = 0.0f;
        for (int chunk = beg; chunk < end; chunk += 64) {
            int j = chunk + lane;
            if (j < end) {
                int s = csr_src[j];
                s_src[lane] = s;
                #pragma unroll
                for (int h = 0; h < H; ++h) {
                    float x = el[s * H + h] + erh[h];
                    x = (x > 0.0f) ? x : (NEGS * x);
                    float w = __expf(x);
                    s_alpha[lane * H + h] = w;
                    wsum[h] += w;
                }
            }
            __syncthreads();
            int cnt = min(64, end - chunk);
            for (int t = 0; t < cnt; ++t) {
                const float* fr = feat + (size_t)s_src[t] * HD;
                #pragma unroll
                for (int r = 0; r < SLOTS; ++r) {
                    int hd = r * 64 + lane;
                    if (hd < HD)
                        acc[r] += s_alpha[t * H + hd / D] * fr[hd];
                }
            }
            __syncthreads();
        }
        #pragma unroll
        for (int h = 0; h < H; ++h) {
            #pragma unroll
            for (int off = 32; off; off >>= 1)
                wsum[h] += __shfl_xor(wsum[h], off, 64);
        }
        #pragma unroll
        for (int r = 0; r < SLOTS; ++r) {
            int hd = r * 64 + lane;
            if (hd < HD) {
                float ws = wsum[hd / D];
                float v = acc[r] * ((ws > 0.0f) ? 1.0f / ws : 0.0f);
                if (relu_mode == 2) v += res[(size_t)n * HD + hd];
                if (relu_mode) v = fmaxf(v, 0.0f);
                out[(size_t)n * HD + hd] = v;
            }
        }
    }
}

// ---------------- residual: res = norm_dst * sum_in(rawn[src]), float4 ----
__global__ void k_res_gather4(const int* __restrict__ rowptr, const int* __restrict__ csr_src,
                              const float* __restrict__ rawn, const float* __restrict__ norm,
                              float* __restrict__ res, int N) {
    constexpr int M4 = 40;
    int i = blockIdx.x * blockDim.x + threadIdx.x;
    if (i >= N * M4) return;
    int n = i / M4, q = i - n * M4;
    int beg = rowptr[n], end = rowptr[n + 1];
    float4 acc = make_float4(0.f, 0.f, 0.f, 0.f);
    for (int j = beg; j < end; ++j) {
        const float4 v = *reinterpret_cast<const float4*>(
            rawn + (size_t)csr_src[j] * 160 + q * 4);
        acc.x += v.x; acc.y += v.y; acc.z += v.z; acc.w += v.w;
    }
    float sc = norm[n];
    acc.x *= sc; acc.y *= sc; acc.z *= sc; acc.w *= sc;
    *reinterpret_cast<float4*>(res + (size_t)n * 160 + q * 4) = acc;
}

// ---------------- launch ----------------
extern "C" void kernel_launch(void* const* d_in, const int* in_sizes, int n_in,
                              void* d_out, int out_size, void* d_ws, size_t ws_size,
                              hipStream_t stream) {
    const float* features = (const float*)d_in[0];
    const int*   src      = (const int*)d_in[1];
    const int*   dst      = (const int*)d_in[2];
    const float* W0   = (const float*)d_in[3];
    const float* al0  = (const float*)d_in[4];
    const float* ar0  = (const float*)d_in[5];
    const float* W1   = (const float*)d_in[6];
    const float* al1  = (const float*)d_in[7];
    const float* ar1  = (const float*)d_in[8];
    const float* W2   = (const float*)d_in[9];
    const float* al2  = (const float*)d_in[10];
    const float* ar2  = (const float*)d_in[11];
    const float* Wout = (const float*)d_in[12];
    const float* alout= (const float*)d_in[13];
    const float* arout= (const float*)d_in[14];
    const float* Wraw = (const float*)d_in[15];
    const float* braw = (const float*)d_in[16];

    const int IN = 300, INP = 320, H = 5, D = 32, HD = 160, OUT = 10;
    const int N = in_sizes[0] / IN;   // 50000
    const int E = in_sizes[1];        // 800000

    char* w = (char*)d_ws;
    auto take = [&](size_t bytes) { char* r = w; w += (bytes + 255) & ~size_t(255); return r; };
    int*   deg     = (int*)  take((size_t)N * 4);
    int*   cnt     = (int*)  take((size_t)N * 4);
    int*   rowptr  = (int*)  take((size_t)(N + 1) * 4);
    int*   csr_src = (int*)  take((size_t)E * 4);
    int*   bsum    = (int*)  take(256 * 4);
    int*   boff    = (int*)  take(256 * 4);
    float* norm    = (float*)take((size_t)N * 4);
    float* el      = (float*)take((size_t)N * H * 4);
    float* er      = (float*)take((size_t)N * H * 4);
    float* res     = (float*)take((size_t)N * HD * 4);
    float* featP   = (float*)take((size_t)N * HD * 4);
    float* hbuf    = (float*)take((size_t)N * HD * 4);
    unsigned short* fhi = (unsigned short*)take((size_t)N * INP * 2);
    unsigned short* flo = (unsigned short*)take((size_t)N * INP * 2);
    unsigned short* wrh = (unsigned short*)take((size_t)160 * INP * 2);
    unsigned short* wrl = (unsigned short*)take((size_t)160 * INP * 2);
    unsigned short* w0h = (unsigned short*)take((size_t)160 * INP * 2);
    unsigned short* w0l = (unsigned short*)take((size_t)160 * INP * 2);
    unsigned short* w1h = (unsigned short*)take((size_t)160 * HD * 2);
    unsigned short* w1l = (unsigned short*)take((size_t)160 * HD * 2);
    unsigned short* w2h = (unsigned short*)take((size_t)160 * HD * 2);
    unsigned short* w2l = (unsigned short*)take((size_t)160 * HD * 2);
    float* out = (float*)d_out;

    unsigned short* hAhi = fhi;
    unsigned short* hAlo = fhi + (size_t)N * HD;
    unsigned short* hBhi = flo;
    unsigned short* hBlo = flo + (size_t)N * HD;

    auto cdiv = [](long long a, long long b) { return (int)((a + b - 1) / b); };
    const int nb = cdiv(N, 256);

    // 1. CSR build + norm (hierarchical scan)
    hipMemsetAsync(deg, 0, (size_t)N * 4, stream);
    hipMemsetAsync(cnt, 0, (size_t)N * 4, stream);
    k_degi<<<cdiv(E, 256), 256, 0, stream>>>(dst, deg, E);
    k_scan1<<<nb, 256, 0, stream>>>(deg, rowptr, bsum, norm, N);
    k_scan2<<<1, 256, 0, stream>>>(bsum, boff, rowptr + N, nb);
    k_scan3<<<nb, 256, 0, stream>>>(rowptr, boff, N);
    k_fill<<<cdiv(E, 256), 256, 0, stream>>>(src, dst, rowptr, cnt, csr_src, E);

    // 2. weight transposes + splits, feature split
    k_splitWT<<<cdiv(160 * INP, 256), 256, 0, stream>>>(Wraw, wrh, wrl, IN, INP);
    k_splitWT<<<cdiv(160 * INP, 256), 256, 0, stream>>>(W0, w0h, w0l, IN, INP);
    k_splitWT<<<cdiv(160 * HD, 256), 256, 0, stream>>>(W1, w1h, w1l, HD, HD);
    k_splitWT<<<cdiv(160 * HD, 256), 256, 0, stream>>>(W2, w2h, w2l, HD, HD);
    k_splitX<<<cdiv((long long)N * INP, 256), 256, 0, stream>>>(features, fhi, flo, N, IN, INP);

    // 3. rawn = (features @ Wraw + braw) * norm
    k_gemm_mfma32<320><<<cdiv(N, 128), 256, 0, stream>>>(fhi, flo, wrh, wrl, braw, norm, featP, N);

    // 4. res = norm * gather_sum(rawn[src])
    k_res_gather4<<<cdiv((long long)N * 40, 256), 256, 0, stream>>>(rowptr, csr_src, featP, norm, res, N);

    // 5. layer 0 (K=300 padded 320)
    k_gemm_mfma32<320><<<cdiv(N, 128), 256, 0, stream>>>(fhi, flo, w0h, w0l, nullptr, nullptr, featP, N);
    k_elr32<<<cdiv((long long)N * H, 256), 256, 0, stream>>>(featP, al0, ar0, el, er, N, H);
    k_gat_fused<5, 32><<<N, 64, 0, stream>>>(rowptr, csr_src, el, er, featP, nullptr,
                                             hbuf, hAhi, hAlo, 1);

    // 6. layer 1 (K=160)
    k_gemm_mfma32<160><<<cdiv(N, 128), 256, 0, stream>>>(hAhi, hAlo, w1h, w1l, nullptr, nullptr, featP, N);
    k_elr32<<<cdiv((long long)N * H, 256), 256, 0, stream>>>(featP, al1, ar1, el, er, N, H);
    k_gat_fused<5, 32><<<N, 64, 0, stream>>>(rowptr, csr_src, el, er, featP, res,
                                             hbuf, hBhi, hBlo, 2);

    // 7. layer 2 (K=160)
    k_gemm_mfma32<160><<<cdiv(N, 128), 256, 0, stream>>>(hBhi, hBlo, w2h, w2l, nullptr, nullptr, featP, N);
    k_elr32<<<cdiv((long long)N * H, 256), 256, 0, stream>>>(featP, al2, ar2, el, er, N, H);
    k_gat_fused<5, 32><<<N, 64, 0, stream>>>(rowptr, csr_src, el, er, featP, res,
                                             hbuf, nullptr, nullptr, 2);

    // 8. output GAT (H=1, D=OUT)
    k_gemv10<<<cdiv(N, 256), 256, 0, stream>>>(hbuf, Wout, featP, N, HD);
    k_elr_gen<<<cdiv(N, 256), 256, 0, stream>>>(featP, alout, arout, el, er, N, 1, OUT);
    k_gat_fused<1, 10><<<N, 64, 0, stream>>>(rowptr, csr_src, el, er, featP, nullptr,
                                             out, nullptr, nullptr, 0);
}